// Round 1
// baseline (925.007 us; speedup 1.0000x reference)
//
#include <hip/hip_runtime.h>

#define NN 50000

// ---------------- degree / normalization ----------------

__global__ __launch_bounds__(256) void deg_kernel(const int* __restrict__ dst, int E,
                                                  int* __restrict__ deg) {
    int i = blockIdx.x * 256 + threadIdx.x;
    if (i < E) atomicAdd(&deg[dst[i]], 1);
}

__global__ __launch_bounds__(256) void dinv_kernel(const int* __restrict__ degS,
                                                   const int* __restrict__ degD,
                                                   float* __restrict__ dinvS,
                                                   float* __restrict__ dinvD, int n) {
    int i = blockIdx.x * 256 + threadIdx.x;
    if (i < n) {
        dinvS[i] = rsqrtf((float)degS[i] + 1.0f);  // +1 self loop
        dinvD[i] = rsqrtf((float)degD[i] + 1.0f);
    }
}

// ---------------- dual GEMM: Ya = X@Wa, Yb = X@Wb  (X:[n,64], W:[64,64]) ----------------

__global__ __launch_bounds__(256) void gemm_dual(const float* __restrict__ X,
                                                 const float* __restrict__ Wa,
                                                 const float* __restrict__ Wb,
                                                 float* __restrict__ Ya,
                                                 float* __restrict__ Yb, int n) {
    int row = blockIdx.x * 256 + threadIdx.x;
    if (row >= n) return;
    float xr[64];
    const float4* xv = reinterpret_cast<const float4*>(X + (size_t)row * 64);
#pragma unroll
    for (int q = 0; q < 16; q++) {
        float4 t = xv[q];
        xr[4 * q + 0] = t.x; xr[4 * q + 1] = t.y;
        xr[4 * q + 2] = t.z; xr[4 * q + 3] = t.w;
    }
#pragma unroll
    for (int r = 0; r < 2; r++) {
        const float* __restrict__ W = (r == 0) ? Wa : Wb;
        float* __restrict__ Y = ((r == 0) ? Ya : Yb) + (size_t)row * 64;
        for (int jt = 0; jt < 4; jt++) {
            float acc[16];
#pragma unroll
            for (int j = 0; j < 16; j++) acc[j] = 0.0f;
#pragma unroll 8
            for (int k = 0; k < 64; k++) {
                float xk = xr[k];
#pragma unroll
                for (int j = 0; j < 16; j++)
                    acc[j] = fmaf(xk, W[k * 64 + jt * 16 + j], acc[j]);
            }
            float4* yo = reinterpret_cast<float4*>(Y + jt * 16);
            yo[0] = make_float4(acc[0], acc[1], acc[2], acc[3]);
            yo[1] = make_float4(acc[4], acc[5], acc[6], acc[7]);
            yo[2] = make_float4(acc[8], acc[9], acc[10], acc[11]);
            yo[3] = make_float4(acc[12], acc[13], acc[14], acc[15]);
        }
    }
}

// ---------------- edge scatter: acc[dst] += dinv[src]*dinv[dst] * h[src] ----------------
// one wave (64 lanes) per edge; lane = feature index

__global__ __launch_bounds__(256) void scatter_kernel(const int* __restrict__ src,
                                                      const int* __restrict__ dst, int E,
                                                      const float* __restrict__ h,
                                                      const float* __restrict__ dinv,
                                                      float* __restrict__ acc) {
    int idx = blockIdx.x * 256 + threadIdx.x;
    int e = idx >> 6;
    if (e >= E) return;
    int lane = idx & 63;
    int s = src[e];
    int d = dst[e];
    float nm = dinv[s] * dinv[d];
    atomicAdd(acc + ((size_t)d * 64 + lane), nm * h[(size_t)s * 64 + lane]);
}

// ---------------- combine: out = relu(acc + dinvS^2*ha + dinvD^2*hb + ba + bb) ----------------

__global__ __launch_bounds__(256) void combine_kernel(const float* __restrict__ acc,
                                                      const float* __restrict__ ha,
                                                      const float* __restrict__ hb,
                                                      const float* __restrict__ dinvS,
                                                      const float* __restrict__ dinvD,
                                                      const float* __restrict__ ba,
                                                      const float* __restrict__ bb,
                                                      float* __restrict__ out, int n) {
    int i = blockIdx.x * 256 + threadIdx.x;  // over n*16 float4 groups
    int total = n * 16;
    if (i >= total) return;
    int node = i >> 4;
    int q = i & 15;
    float ds = dinvS[node]; ds = ds * ds;
    float dd = dinvD[node]; dd = dd * dd;
    float4 a = reinterpret_cast<const float4*>(acc)[i];
    float4 xa = reinterpret_cast<const float4*>(ha)[i];
    float4 xb = reinterpret_cast<const float4*>(hb)[i];
    float4 bs = reinterpret_cast<const float4*>(ba)[q];
    float4 bd = reinterpret_cast<const float4*>(bb)[q];
    float4 o;
    o.x = fmaxf(a.x + ds * xa.x + dd * xb.x + bs.x + bd.x, 0.0f);
    o.y = fmaxf(a.y + ds * xa.y + dd * xb.y + bs.y + bd.y, 0.0f);
    o.z = fmaxf(a.z + ds * xa.z + dd * xb.z + bs.z + bd.z, 0.0f);
    o.w = fmaxf(a.w + ds * xa.w + dd * xb.w + bs.w + bd.w, 0.0f);
    reinterpret_cast<float4*>(out)[i] = o;
}

// ---------------- final linear: out[n,3] = h@Wlin + blin ----------------

__global__ __launch_bounds__(256) void final_kernel(const float* __restrict__ h,
                                                    const float* __restrict__ Wlin,
                                                    const float* __restrict__ blin,
                                                    float* __restrict__ out, int n) {
    int row = blockIdx.x * 256 + threadIdx.x;
    if (row >= n) return;
    float a0 = blin[0], a1 = blin[1], a2 = blin[2];
    const float4* hv = reinterpret_cast<const float4*>(h + (size_t)row * 64);
#pragma unroll
    for (int q = 0; q < 16; q++) {
        float4 t = hv[q];
        int k = 4 * q;
        a0 = fmaf(t.x, Wlin[(k + 0) * 3 + 0], a0);
        a1 = fmaf(t.x, Wlin[(k + 0) * 3 + 1], a1);
        a2 = fmaf(t.x, Wlin[(k + 0) * 3 + 2], a2);
        a0 = fmaf(t.y, Wlin[(k + 1) * 3 + 0], a0);
        a1 = fmaf(t.y, Wlin[(k + 1) * 3 + 1], a1);
        a2 = fmaf(t.y, Wlin[(k + 1) * 3 + 2], a2);
        a0 = fmaf(t.z, Wlin[(k + 2) * 3 + 0], a0);
        a1 = fmaf(t.z, Wlin[(k + 2) * 3 + 1], a1);
        a2 = fmaf(t.z, Wlin[(k + 2) * 3 + 2], a2);
        a0 = fmaf(t.w, Wlin[(k + 3) * 3 + 0], a0);
        a1 = fmaf(t.w, Wlin[(k + 3) * 3 + 1], a1);
        a2 = fmaf(t.w, Wlin[(k + 3) * 3 + 2], a2);
    }
    out[row * 3 + 0] = a0;
    out[row * 3 + 1] = a1;
    out[row * 3 + 2] = a2;
}

extern "C" void kernel_launch(void* const* d_in, const int* in_sizes, int n_in,
                              void* d_out, int out_size, void* d_ws, size_t ws_size,
                              hipStream_t stream) {
    const float* x    = (const float*)d_in[0];
    const int*   eis  = (const int*)d_in[1];
    const int*   eid  = (const int*)d_in[2];
    const float* W1s  = (const float*)d_in[3];
    const float* b1s  = (const float*)d_in[4];
    const float* W1d  = (const float*)d_in[5];
    const float* b1d  = (const float*)d_in[6];
    const float* W2s  = (const float*)d_in[7];
    const float* b2s  = (const float*)d_in[8];
    const float* W2d  = (const float*)d_in[9];
    const float* b2d  = (const float*)d_in[10];
    const float* Wlin = (const float*)d_in[11];
    const float* blin = (const float*)d_in[12];

    const int N  = NN;
    const int Es = in_sizes[1] / 2;
    const int Ed = in_sizes[2] / 2;

    // workspace layout
    int*   degS  = (int*)d_ws;
    int*   degD  = degS + N;
    float* dinvS = (float*)(degD + N);
    float* dinvD = dinvS + N;
    float* bufA  = dinvD + N;                   // hs  [N,64]
    float* bufB  = bufA + (size_t)N * 64;       // hd  [N,64]
    float* bufAcc = bufB + (size_t)N * 64;      // edge accumulator [N,64]
    float* bufH  = bufAcc + (size_t)N * 64;     // layer output [N,64]

    // degrees + normalization (recomputed every call: deterministic)
    hipMemsetAsync(degS, 0, (size_t)2 * N * sizeof(int), stream);
    deg_kernel<<<(Es + 255) / 256, 256, 0, stream>>>(eis + Es, Es, degS);
    deg_kernel<<<(Ed + 255) / 256, 256, 0, stream>>>(eid + Ed, Ed, degD);
    dinv_kernel<<<(N + 255) / 256, 256, 0, stream>>>(degS, degD, dinvS, dinvD, N);

    // ---- layer 1 ----
    gemm_dual<<<(N + 255) / 256, 256, 0, stream>>>(x, W1s, W1d, bufA, bufB, N);
    hipMemsetAsync(bufAcc, 0, (size_t)N * 64 * sizeof(float), stream);
    {
        int blocksS = (Es * 64 + 255) / 256;
        int blocksD = (Ed * 64 + 255) / 256;
        scatter_kernel<<<blocksS, 256, 0, stream>>>(eis, eis + Es, Es, bufA, dinvS, bufAcc);
        scatter_kernel<<<blocksD, 256, 0, stream>>>(eid, eid + Ed, Ed, bufB, dinvD, bufAcc);
    }
    combine_kernel<<<(N * 16 + 255) / 256, 256, 0, stream>>>(bufAcc, bufA, bufB, dinvS, dinvD,
                                                             b1s, b1d, bufH, N);

    // ---- layer 2 ----
    gemm_dual<<<(N + 255) / 256, 256, 0, stream>>>(bufH, W2s, W2d, bufA, bufB, N);
    hipMemsetAsync(bufAcc, 0, (size_t)N * 64 * sizeof(float), stream);
    {
        int blocksS = (Es * 64 + 255) / 256;
        int blocksD = (Ed * 64 + 255) / 256;
        scatter_kernel<<<blocksS, 256, 0, stream>>>(eis, eis + Es, Es, bufA, dinvS, bufAcc);
        scatter_kernel<<<blocksD, 256, 0, stream>>>(eid, eid + Ed, Ed, bufB, dinvD, bufAcc);
    }
    combine_kernel<<<(N * 16 + 255) / 256, 256, 0, stream>>>(bufAcc, bufA, bufB, dinvS, dinvD,
                                                             b2s, b2d, bufH, N);

    // ---- output head ----
    final_kernel<<<(N + 255) / 256, 256, 0, stream>>>(bufH, Wlin, blin, (float*)d_out, N);
}

// Round 2
// 571.405 us; speedup vs baseline: 1.6188x; 1.6188x over previous
//
#include <hip/hip_runtime.h>

#define NN 50000

// ---------------- degree counting ----------------

__global__ __launch_bounds__(256) void deg_kernel(const int* __restrict__ dst, int E,
                                                  int* __restrict__ deg) {
    int i = blockIdx.x * 256 + threadIdx.x;
    if (i < E) atomicAdd(&deg[dst[i]], 1);
}

__global__ __launch_bounds__(256) void dinv_kernel(const int* __restrict__ degS,
                                                   const int* __restrict__ degD,
                                                   float* __restrict__ dinvS,
                                                   float* __restrict__ dinvD, int n) {
    int i = blockIdx.x * 256 + threadIdx.x;
    if (i < n) {
        dinvS[i] = rsqrtf((float)degS[i] + 1.0f);  // +1 self loop
        dinvD[i] = rsqrtf((float)degD[i] + 1.0f);
    }
}

// ---------------- exclusive prefix scan (one workgroup per relation) ----------------
// grid = 2 blocks x 1024 threads; block 0 scans S, block 1 scans D.

__global__ __launch_bounds__(1024) void scan2_kernel(const int* __restrict__ degS,
                                                     const int* __restrict__ degD,
                                                     int* __restrict__ offsS,
                                                     int* __restrict__ offsD,
                                                     int* __restrict__ curS,
                                                     int* __restrict__ curD, int n) {
    const int* deg = (blockIdx.x == 0) ? degS : degD;
    int* offs      = (blockIdx.x == 0) ? offsS : offsD;
    int* cur       = (blockIdx.x == 0) ? curS : curD;

    __shared__ int buf[2][1024];
    __shared__ int carry_s;
    int tid = threadIdx.x;
    if (tid == 0) carry_s = 0;
    __syncthreads();
    int nchunk = (n + 1023) / 1024;
    for (int c = 0; c < nchunk; ++c) {
        int i = c * 1024 + tid;
        int v = (i < n) ? deg[i] : 0;
        buf[0][tid] = v;
        __syncthreads();
        int pp = 0;
        for (int st = 1; st < 1024; st <<= 1) {
            int x = buf[pp][tid];
            if (tid >= st) x += buf[pp][tid - st];
            buf[pp ^ 1][tid] = x;
            pp ^= 1;
            __syncthreads();
        }
        int incl = buf[pp][tid];
        int base = carry_s;
        if (i < n) {
            int excl = base + incl - v;
            offs[i] = excl;
            cur[i] = excl;
        }
        __syncthreads();
        if (tid == 1023) carry_s = base + incl;
        __syncthreads();
    }
    if (tid == 0) offs[n] = carry_s;
}

// ---------------- CSR fill ----------------

__global__ __launch_bounds__(256) void fill_kernel(const int* __restrict__ src,
                                                   const int* __restrict__ dst, int E,
                                                   int* __restrict__ cur,
                                                   int* __restrict__ srcArr) {
    int i = blockIdx.x * 256 + threadIdx.x;
    if (i < E) {
        int d = dst[i];
        int p = atomicAdd(&cur[d], 1);
        srcArr[p] = src[i];
    }
}

// ---------------- dual GEMM with dinv pre-scale epilogue ----------------
// Ya = dinvA[row] * (X@Wa),  Yb = dinvB[row] * (X@Wb)

__global__ __launch_bounds__(256) void gemm_dual(const float* __restrict__ X,
                                                 const float* __restrict__ Wa,
                                                 const float* __restrict__ Wb,
                                                 const float* __restrict__ dinvA,
                                                 const float* __restrict__ dinvB,
                                                 float* __restrict__ Ya,
                                                 float* __restrict__ Yb, int n) {
    int row = blockIdx.x * 256 + threadIdx.x;
    if (row >= n) return;
    float xr[64];
    const float4* xv = reinterpret_cast<const float4*>(X + (size_t)row * 64);
#pragma unroll
    for (int q = 0; q < 16; q++) {
        float4 t = xv[q];
        xr[4 * q + 0] = t.x; xr[4 * q + 1] = t.y;
        xr[4 * q + 2] = t.z; xr[4 * q + 3] = t.w;
    }
#pragma unroll
    for (int r = 0; r < 2; r++) {
        const float* __restrict__ W = (r == 0) ? Wa : Wb;
        float sc = (r == 0) ? dinvA[row] : dinvB[row];
        float* __restrict__ Y = ((r == 0) ? Ya : Yb) + (size_t)row * 64;
        for (int jt = 0; jt < 4; jt++) {
            float acc[16];
#pragma unroll
            for (int j = 0; j < 16; j++) acc[j] = 0.0f;
#pragma unroll 8
            for (int k = 0; k < 64; k++) {
                float xk = xr[k];
#pragma unroll
                for (int j = 0; j < 16; j++)
                    acc[j] = fmaf(xk, W[k * 64 + jt * 16 + j], acc[j]);
            }
            float4* yo = reinterpret_cast<float4*>(Y + jt * 16);
            yo[0] = make_float4(sc * acc[0], sc * acc[1], sc * acc[2], sc * acc[3]);
            yo[1] = make_float4(sc * acc[4], sc * acc[5], sc * acc[6], sc * acc[7]);
            yo[2] = make_float4(sc * acc[8], sc * acc[9], sc * acc[10], sc * acc[11]);
            yo[3] = make_float4(sc * acc[12], sc * acc[13], sc * acc[14], sc * acc[15]);
        }
    }
}

// ---------------- fused gather + combine ----------------
// one wave per dst node, lane = feature index
// out[d] = relu( dinvS[d]*(hpS[d] + sum hpS[src]) + dinvD[d]*(hpD[d] + sum hpD[src]) + ba + bb )

__global__ __launch_bounds__(256) void gather_fused(const int* __restrict__ offsS,
                                                    const int* __restrict__ srcS,
                                                    const int* __restrict__ offsD,
                                                    const int* __restrict__ srcD,
                                                    const float* __restrict__ hpS,
                                                    const float* __restrict__ hpD,
                                                    const float* __restrict__ dinvS,
                                                    const float* __restrict__ dinvD,
                                                    const float* __restrict__ ba,
                                                    const float* __restrict__ bb,
                                                    float* __restrict__ out, int n) {
    int wid = (blockIdx.x * 256 + threadIdx.x) >> 6;
    int lane = threadIdx.x & 63;
    if (wid >= n) return;

    // relation S
    float accS = hpS[(size_t)wid * 64 + lane];
    {
        int e0 = offsS[wid], e1 = offsS[wid + 1];
        float acc2 = 0.0f;
        int e = e0;
        for (; e + 1 < e1; e += 2) {
            int s0 = srcS[e];
            int s1 = srcS[e + 1];
            accS += hpS[(size_t)s0 * 64 + lane];
            acc2 += hpS[(size_t)s1 * 64 + lane];
        }
        if (e < e1) accS += hpS[(size_t)srcS[e] * 64 + lane];
        accS += acc2;
    }

    // relation D
    float accD = hpD[(size_t)wid * 64 + lane];
    {
        int e0 = offsD[wid], e1 = offsD[wid + 1];
        float acc2 = 0.0f;
        int e = e0;
        for (; e + 1 < e1; e += 2) {
            int s0 = srcD[e];
            int s1 = srcD[e + 1];
            accD += hpD[(size_t)s0 * 64 + lane];
            acc2 += hpD[(size_t)s1 * 64 + lane];
        }
        if (e < e1) accD += hpD[(size_t)srcD[e] * 64 + lane];
        accD += acc2;
    }

    float v = dinvS[wid] * accS + dinvD[wid] * accD + ba[lane] + bb[lane];
    out[(size_t)wid * 64 + lane] = fmaxf(v, 0.0f);
}

// ---------------- final linear: out[n,3] = h@Wlin + blin ----------------

__global__ __launch_bounds__(256) void final_kernel(const float* __restrict__ h,
                                                    const float* __restrict__ Wlin,
                                                    const float* __restrict__ blin,
                                                    float* __restrict__ out, int n) {
    int row = blockIdx.x * 256 + threadIdx.x;
    if (row >= n) return;
    float a0 = blin[0], a1 = blin[1], a2 = blin[2];
    const float4* hv = reinterpret_cast<const float4*>(h + (size_t)row * 64);
#pragma unroll
    for (int q = 0; q < 16; q++) {
        float4 t = hv[q];
        int k = 4 * q;
        a0 = fmaf(t.x, Wlin[(k + 0) * 3 + 0], a0);
        a1 = fmaf(t.x, Wlin[(k + 0) * 3 + 1], a1);
        a2 = fmaf(t.x, Wlin[(k + 0) * 3 + 2], a2);
        a0 = fmaf(t.y, Wlin[(k + 1) * 3 + 0], a0);
        a1 = fmaf(t.y, Wlin[(k + 1) * 3 + 1], a1);
        a2 = fmaf(t.y, Wlin[(k + 1) * 3 + 2], a2);
        a0 = fmaf(t.z, Wlin[(k + 2) * 3 + 0], a0);
        a1 = fmaf(t.z, Wlin[(k + 2) * 3 + 1], a1);
        a2 = fmaf(t.z, Wlin[(k + 2) * 3 + 2], a2);
        a0 = fmaf(t.w, Wlin[(k + 3) * 3 + 0], a0);
        a1 = fmaf(t.w, Wlin[(k + 3) * 3 + 1], a1);
        a2 = fmaf(t.w, Wlin[(k + 3) * 3 + 2], a2);
    }
    out[row * 3 + 0] = a0;
    out[row * 3 + 1] = a1;
    out[row * 3 + 2] = a2;
}

extern "C" void kernel_launch(void* const* d_in, const int* in_sizes, int n_in,
                              void* d_out, int out_size, void* d_ws, size_t ws_size,
                              hipStream_t stream) {
    const float* x    = (const float*)d_in[0];
    const int*   eis  = (const int*)d_in[1];
    const int*   eid  = (const int*)d_in[2];
    const float* W1s  = (const float*)d_in[3];
    const float* b1s  = (const float*)d_in[4];
    const float* W1d  = (const float*)d_in[5];
    const float* b1d  = (const float*)d_in[6];
    const float* W2s  = (const float*)d_in[7];
    const float* b2s  = (const float*)d_in[8];
    const float* W2d  = (const float*)d_in[9];
    const float* b2d  = (const float*)d_in[10];
    const float* Wlin = (const float*)d_in[11];
    const float* blin = (const float*)d_in[12];

    const int N  = NN;
    const int Es = in_sizes[1] / 2;
    const int Ed = in_sizes[2] / 2;

    // workspace layout (element offsets, 4B each)
    int*   degS  = (int*)d_ws;                 // [0, N)
    int*   degD  = degS + N;                   // [N, 2N)
    float* dinvS = (float*)(degD + N);         // [2N, 3N)
    float* dinvD = dinvS + N;                  // [3N, 4N)
    int*   offsS = (int*)(dinvD + N);          // N+1, padded to N+4
    int*   offsD = offsS + (N + 4);
    int*   curS  = offsD + (N + 4);
    int*   curD  = curS + N;
    int*   srcS  = curD + N;                   // [Es]
    int*   srcD  = srcS + Es;                  // [Ed]
    float* bufA  = (float*)(srcD + Ed);        // [N*64] pre-scaled hS'
    float* bufB  = bufA + (size_t)N * 64;      // [N*64] pre-scaled hD'
    float* bufH  = bufB + (size_t)N * 64;      // [N*64] layer output

    // ---- graph preprocessing (once per call, reused by both layers) ----
    hipMemsetAsync(degS, 0, (size_t)2 * N * sizeof(int), stream);
    deg_kernel<<<(Es + 255) / 256, 256, 0, stream>>>(eis + Es, Es, degS);
    deg_kernel<<<(Ed + 255) / 256, 256, 0, stream>>>(eid + Ed, Ed, degD);
    dinv_kernel<<<(N + 255) / 256, 256, 0, stream>>>(degS, degD, dinvS, dinvD, N);
    scan2_kernel<<<2, 1024, 0, stream>>>(degS, degD, offsS, offsD, curS, curD, N);
    fill_kernel<<<(Es + 255) / 256, 256, 0, stream>>>(eis, eis + Es, Es, curS, srcS);
    fill_kernel<<<(Ed + 255) / 256, 256, 0, stream>>>(eid, eid + Ed, Ed, curD, srcD);

    int gatherBlocks = (N * 64 + 255) / 256;

    // ---- layer 1 ----
    gemm_dual<<<(N + 255) / 256, 256, 0, stream>>>(x, W1s, W1d, dinvS, dinvD, bufA, bufB, N);
    gather_fused<<<gatherBlocks, 256, 0, stream>>>(offsS, srcS, offsD, srcD, bufA, bufB,
                                                   dinvS, dinvD, b1s, b1d, bufH, N);

    // ---- layer 2 ----
    gemm_dual<<<(N + 255) / 256, 256, 0, stream>>>(bufH, W2s, W2d, dinvS, dinvD, bufA, bufB, N);
    gather_fused<<<gatherBlocks, 256, 0, stream>>>(offsS, srcS, offsD, srcD, bufA, bufB,
                                                   dinvS, dinvD, b2s, b2d, bufH, N);

    // ---- output head ----
    final_kernel<<<(N + 255) / 256, 256, 0, stream>>>(bufH, Wlin, blin, (float*)d_out, N);
}

// Round 3
// 544.716 us; speedup vs baseline: 1.6981x; 1.0490x over previous
//
#include <hip/hip_runtime.h>

#define NN 50000

// ---------------- degree counting (both relations in one dispatch) ----------------

__global__ __launch_bounds__(256) void deg_both(const int* __restrict__ dstS, int Es,
                                                const int* __restrict__ dstD, int Ed,
                                                int* __restrict__ degS,
                                                int* __restrict__ degD) {
    int i = blockIdx.x * 256 + threadIdx.x;
    if (i < Es) atomicAdd(&degS[dstS[i]], 1);
    if (i < Ed) atomicAdd(&degD[dstD[i]], 1);
}

// ---------------- exclusive prefix scan + dinv (one workgroup per relation) ----------------

__global__ __launch_bounds__(1024) void scan2_kernel(const int* __restrict__ degS,
                                                     const int* __restrict__ degD,
                                                     int* __restrict__ offsS,
                                                     int* __restrict__ offsD,
                                                     int* __restrict__ curS,
                                                     int* __restrict__ curD,
                                                     float* __restrict__ dinvS,
                                                     float* __restrict__ dinvD, int n) {
    const int* deg = (blockIdx.x == 0) ? degS : degD;
    int* offs      = (blockIdx.x == 0) ? offsS : offsD;
    int* cur       = (blockIdx.x == 0) ? curS : curD;
    float* dinv    = (blockIdx.x == 0) ? dinvS : dinvD;

    __shared__ int buf[2][1024];
    __shared__ int carry_s;
    int tid = threadIdx.x;
    if (tid == 0) carry_s = 0;
    __syncthreads();
    int nchunk = (n + 1023) / 1024;
    for (int c = 0; c < nchunk; ++c) {
        int i = c * 1024 + tid;
        int v = (i < n) ? deg[i] : 0;
        buf[0][tid] = v;
        __syncthreads();
        int pp = 0;
        for (int st = 1; st < 1024; st <<= 1) {
            int x = buf[pp][tid];
            if (tid >= st) x += buf[pp][tid - st];
            buf[pp ^ 1][tid] = x;
            pp ^= 1;
            __syncthreads();
        }
        int incl = buf[pp][tid];
        int base = carry_s;
        if (i < n) {
            int excl = base + incl - v;
            offs[i] = excl;
            cur[i] = excl;
            dinv[i] = rsqrtf((float)v + 1.0f);  // +1 self loop
        }
        __syncthreads();
        if (tid == 1023) carry_s = base + incl;
        __syncthreads();
    }
    if (tid == 0) offs[n] = carry_s;
}

// ---------------- CSR fill (both relations) ----------------

__global__ __launch_bounds__(256) void fill_both(const int* __restrict__ eiS, int Es,
                                                 const int* __restrict__ eiD, int Ed,
                                                 int* __restrict__ curS,
                                                 int* __restrict__ curD,
                                                 int* __restrict__ srcS,
                                                 int* __restrict__ srcD) {
    int i = blockIdx.x * 256 + threadIdx.x;
    if (i < Es) {
        int p = atomicAdd(&curS[eiS[Es + i]], 1);
        srcS[p] = eiS[i];
    }
    if (i < Ed) {
        int p = atomicAdd(&curD[eiD[Ed + i]], 1);
        srcD[p] = eiD[i];
    }
}

// ---------------- dual GEMM with dinv pre-scale epilogue ----------------

__global__ __launch_bounds__(256) void gemm_dual(const float* __restrict__ X,
                                                 const float* __restrict__ Wa,
                                                 const float* __restrict__ Wb,
                                                 const float* __restrict__ dinvA,
                                                 const float* __restrict__ dinvB,
                                                 float* __restrict__ Ya,
                                                 float* __restrict__ Yb, int n) {
    int row = blockIdx.x * 256 + threadIdx.x;
    if (row >= n) return;
    float xr[64];
    const float4* xv = reinterpret_cast<const float4*>(X + (size_t)row * 64);
#pragma unroll
    for (int q = 0; q < 16; q++) {
        float4 t = xv[q];
        xr[4 * q + 0] = t.x; xr[4 * q + 1] = t.y;
        xr[4 * q + 2] = t.z; xr[4 * q + 3] = t.w;
    }
#pragma unroll
    for (int r = 0; r < 2; r++) {
        const float* __restrict__ W = (r == 0) ? Wa : Wb;
        float sc = (r == 0) ? dinvA[row] : dinvB[row];
        float* __restrict__ Y = ((r == 0) ? Ya : Yb) + (size_t)row * 64;
        for (int jt = 0; jt < 4; jt++) {
            float acc[16];
#pragma unroll
            for (int j = 0; j < 16; j++) acc[j] = 0.0f;
#pragma unroll 8
            for (int k = 0; k < 64; k++) {
                float xk = xr[k];
#pragma unroll
                for (int j = 0; j < 16; j++)
                    acc[j] = fmaf(xk, W[k * 64 + jt * 16 + j], acc[j]);
            }
            float4* yo = reinterpret_cast<float4*>(Y + jt * 16);
            yo[0] = make_float4(sc * acc[0], sc * acc[1], sc * acc[2], sc * acc[3]);
            yo[1] = make_float4(sc * acc[4], sc * acc[5], sc * acc[6], sc * acc[7]);
            yo[2] = make_float4(sc * acc[8], sc * acc[9], sc * acc[10], sc * acc[11]);
            yo[3] = make_float4(sc * acc[12], sc * acc[13], sc * acc[14], sc * acc[15]);
        }
    }
}

// ---------------- fused gather + combine (+ optional linear head) ----------------
// one wave per dst node, lane = feature index.
// Interleaved S/D edge loops, 4-way unroll each -> 8 outstanding row loads.
// HEAD=1: instead of writing h row, compute out[wid,0:3] = relu_row . Wlin + blin.

template <int HEAD>
__global__ __launch_bounds__(256) void gather_fused(const int* __restrict__ offsS,
                                                    const int* __restrict__ srcS,
                                                    const int* __restrict__ offsD,
                                                    const int* __restrict__ srcD,
                                                    const float* __restrict__ hpS,
                                                    const float* __restrict__ hpD,
                                                    const float* __restrict__ dinvS,
                                                    const float* __restrict__ dinvD,
                                                    const float* __restrict__ ba,
                                                    const float* __restrict__ bb,
                                                    const float* __restrict__ Wlin,
                                                    const float* __restrict__ blin,
                                                    float* __restrict__ out, int n) {
    int wid = (blockIdx.x * 256 + threadIdx.x) >> 6;
    int lane = threadIdx.x & 63;
    if (wid >= n) return;

    int eS = offsS[wid], eS1 = offsS[wid + 1];
    int eD = offsD[wid], eD1 = offsD[wid + 1];
    float accS = hpS[(size_t)wid * 64 + lane];  // self loop
    float accD = hpD[(size_t)wid * 64 + lane];

    // steady state: 8 outstanding row loads (4 S + 4 D)
    while (eS + 4 <= eS1 && eD + 4 <= eD1) {
        int s0 = srcS[eS], s1 = srcS[eS + 1], s2 = srcS[eS + 2], s3 = srcS[eS + 3];
        int d0 = srcD[eD], d1 = srcD[eD + 1], d2 = srcD[eD + 2], d3 = srcD[eD + 3];
        float a0 = hpS[(size_t)s0 * 64 + lane];
        float a1 = hpS[(size_t)s1 * 64 + lane];
        float a2 = hpS[(size_t)s2 * 64 + lane];
        float a3 = hpS[(size_t)s3 * 64 + lane];
        float b0 = hpD[(size_t)d0 * 64 + lane];
        float b1 = hpD[(size_t)d1 * 64 + lane];
        float b2 = hpD[(size_t)d2 * 64 + lane];
        float b3 = hpD[(size_t)d3 * 64 + lane];
        accS += (a0 + a1) + (a2 + a3);
        accD += (b0 + b1) + (b2 + b3);
        eS += 4; eD += 4;
    }
    // drain S
    while (eS + 4 <= eS1) {
        int s0 = srcS[eS], s1 = srcS[eS + 1], s2 = srcS[eS + 2], s3 = srcS[eS + 3];
        float a0 = hpS[(size_t)s0 * 64 + lane];
        float a1 = hpS[(size_t)s1 * 64 + lane];
        float a2 = hpS[(size_t)s2 * 64 + lane];
        float a3 = hpS[(size_t)s3 * 64 + lane];
        accS += (a0 + a1) + (a2 + a3);
        eS += 4;
    }
    while (eS < eS1) accS += hpS[(size_t)srcS[eS++] * 64 + lane];
    // drain D
    while (eD + 4 <= eD1) {
        int d0 = srcD[eD], d1 = srcD[eD + 1], d2 = srcD[eD + 2], d3 = srcD[eD + 3];
        float b0 = hpD[(size_t)d0 * 64 + lane];
        float b1 = hpD[(size_t)d1 * 64 + lane];
        float b2 = hpD[(size_t)d2 * 64 + lane];
        float b3 = hpD[(size_t)d3 * 64 + lane];
        accD += (b0 + b1) + (b2 + b3);
        eD += 4;
    }
    while (eD < eD1) accD += hpD[(size_t)srcD[eD++] * 64 + lane];

    float v = dinvS[wid] * accS + dinvD[wid] * accD + ba[lane] + bb[lane];
    v = fmaxf(v, 0.0f);

    if (HEAD == 0) {
        out[(size_t)wid * 64 + lane] = v;
    } else {
#pragma unroll
        for (int j = 0; j < 3; j++) {
            float p = v * Wlin[lane * 3 + j];
#pragma unroll
            for (int st = 32; st >= 1; st >>= 1) p += __shfl_xor(p, st, 64);
            if (lane == 0) out[(size_t)wid * 3 + j] = p + blin[j];
        }
    }
}

extern "C" void kernel_launch(void* const* d_in, const int* in_sizes, int n_in,
                              void* d_out, int out_size, void* d_ws, size_t ws_size,
                              hipStream_t stream) {
    const float* x    = (const float*)d_in[0];
    const int*   eis  = (const int*)d_in[1];
    const int*   eid  = (const int*)d_in[2];
    const float* W1s  = (const float*)d_in[3];
    const float* b1s  = (const float*)d_in[4];
    const float* W1d  = (const float*)d_in[5];
    const float* b1d  = (const float*)d_in[6];
    const float* W2s  = (const float*)d_in[7];
    const float* b2s  = (const float*)d_in[8];
    const float* W2d  = (const float*)d_in[9];
    const float* b2d  = (const float*)d_in[10];
    const float* Wlin = (const float*)d_in[11];
    const float* blin = (const float*)d_in[12];

    const int N  = NN;
    const int Es = in_sizes[1] / 2;
    const int Ed = in_sizes[2] / 2;

    // workspace layout (element offsets, 4B each)
    int*   degS  = (int*)d_ws;                 // [N]
    int*   degD  = degS + N;                   // [N]
    float* dinvS = (float*)(degD + N);         // [N]
    float* dinvD = dinvS + N;                  // [N]
    int*   offsS = (int*)(dinvD + N);          // [N+4]
    int*   offsD = offsS + (N + 4);            // [N+4]
    int*   curS  = offsD + (N + 4);            // [N]
    int*   curD  = curS + N;                   // [N]
    int*   srcS  = curD + N;                   // [Es]
    int*   srcD  = srcS + Es;                  // [Ed]
    float* bufA  = (float*)(srcD + Ed);        // [N*64] pre-scaled hS'
    float* bufB  = bufA + (size_t)N * 64;      // [N*64] pre-scaled hD'
    float* bufH  = bufB + (size_t)N * 64;      // [N*64] layer-1 output

    int Emax = (Es > Ed) ? Es : Ed;

    // ---- graph preprocessing (reused by both layers) ----
    hipMemsetAsync(degS, 0, (size_t)2 * N * sizeof(int), stream);
    deg_both<<<(Emax + 255) / 256, 256, 0, stream>>>(eis + Es, Es, eid + Ed, Ed, degS, degD);
    scan2_kernel<<<2, 1024, 0, stream>>>(degS, degD, offsS, offsD, curS, curD, dinvS, dinvD, N);
    fill_both<<<(Emax + 255) / 256, 256, 0, stream>>>(eis, Es, eid, Ed, curS, curD, srcS, srcD);

    int gatherBlocks = (N * 64 + 255) / 256;

    // ---- layer 1 ----
    gemm_dual<<<(N + 255) / 256, 256, 0, stream>>>(x, W1s, W1d, dinvS, dinvD, bufA, bufB, N);
    gather_fused<0><<<gatherBlocks, 256, 0, stream>>>(offsS, srcS, offsD, srcD, bufA, bufB,
                                                      dinvS, dinvD, b1s, b1d, nullptr, nullptr,
                                                      bufH, N);

    // ---- layer 2 (head fused: writes out[N,3] directly) ----
    gemm_dual<<<(N + 255) / 256, 256, 0, stream>>>(bufH, W2s, W2d, dinvS, dinvD, bufA, bufB, N);
    gather_fused<1><<<gatherBlocks, 256, 0, stream>>>(offsS, srcS, offsD, srcD, bufA, bufB,
                                                      dinvS, dinvD, b2s, b2d, Wlin, blin,
                                                      (float*)d_out, N);
}

// Round 4
// 342.121 us; speedup vs baseline: 2.7037x; 1.5922x over previous
//
#include <hip/hip_runtime.h>

#define NN 50000
#define BSHIFT 8
#define NBK ((NN + 255) >> 8)   // 196 buckets of 256 nodes
#define CHUNK 4096               // edges per workgroup in count/scatter
#define CAP 8192                 // per-bucket record capacity (mean ~4082, +64 sigma safe)

// ---------------- pass A: per-bucket edge counts (LDS histogram) ----------------

__global__ __launch_bounds__(256) void bucket_count(const int* __restrict__ eiS, int Es,
                                                    const int* __restrict__ eiD, int Ed,
                                                    int* __restrict__ cntS,
                                                    int* __restrict__ cntD) {
    __shared__ int h[NBK];
    int rel = blockIdx.y;
    const int* dst = rel ? (eiD + Ed) : (eiS + Es);
    int E = rel ? Ed : Es;
    int* cnt = rel ? cntD : cntS;
    int base = blockIdx.x * CHUNK;
    if (base >= E) return;
    for (int i = threadIdx.x; i < NBK; i += 256) h[i] = 0;
    __syncthreads();
    int end = (base + CHUNK < E) ? base + CHUNK : E;
    for (int e = base + threadIdx.x; e < end; e += 256)
        atomicAdd(&h[dst[e] >> BSHIFT], 1);
    __syncthreads();
    for (int i = threadIdx.x; i < NBK; i += 256)
        if (h[i]) atomicAdd(&cnt[i], h[i]);
}

// ---------------- pass B: scan bucket counts (1 block per relation) ----------------

__global__ __launch_bounds__(256) void bucket_scan(const int* __restrict__ cntS,
                                                   const int* __restrict__ cntD,
                                                   int* __restrict__ baseS,
                                                   int* __restrict__ baseD,
                                                   int* __restrict__ curS,
                                                   int* __restrict__ curD,
                                                   int* __restrict__ offsS,
                                                   int* __restrict__ offsD) {
    __shared__ int sA[256], sB[256];
    const int* cnt = blockIdx.x ? cntD : cntS;
    int* base = blockIdx.x ? baseD : baseS;
    int* cur  = blockIdx.x ? curD : curS;
    int* offs = blockIdx.x ? offsD : offsS;
    int t = threadIdx.x;
    int v = (t < NBK) ? cnt[t] : 0;
    sA[t] = v;
    __syncthreads();
    int* pin = sA; int* pout = sB;
    for (int st = 1; st < 256; st <<= 1) {
        int x = pin[t];
        if (t >= st) x += pin[t - st];
        pout[t] = x;
        __syncthreads();
        int* tmp = pin; pin = pout; pout = tmp;
    }
    int incl = pin[t];
    int excl = incl - v;
    if (t < NBK) { base[t] = excl; cur[t] = excl; }
    if (t == NBK - 1) { base[NBK] = incl; offs[NN] = incl; }
}

// ---------------- pass C: scatter packed records into bucket regions ----------------
// record = (dst & 255) << 16 | src   (src < 65536 since NN = 50000)

__global__ __launch_bounds__(256) void bucket_scatter(const int* __restrict__ eiS, int Es,
                                                      const int* __restrict__ eiD, int Ed,
                                                      int* __restrict__ curS,
                                                      int* __restrict__ curD,
                                                      unsigned* __restrict__ recS,
                                                      unsigned* __restrict__ recD) {
    __shared__ int h[NBK];
    __shared__ int rb[NBK];
    int rel = blockIdx.y;
    const int* ei = rel ? eiD : eiS;
    int E = rel ? Ed : Es;
    int* cur = rel ? curD : curS;
    unsigned* rec = rel ? recD : recS;
    int base = blockIdx.x * CHUNK;
    if (base >= E) return;
    const int* src = ei;
    const int* dst = ei + E;
    int end = (base + CHUNK < E) ? base + CHUNK : E;

    for (int i = threadIdx.x; i < NBK; i += 256) h[i] = 0;
    __syncthreads();
    for (int e = base + threadIdx.x; e < end; e += 256)
        atomicAdd(&h[dst[e] >> BSHIFT], 1);
    __syncthreads();
    for (int i = threadIdx.x; i < NBK; i += 256) {
        int c = h[i];
        rb[i] = c ? atomicAdd(&cur[i], c) : 0;
    }
    __syncthreads();
    for (int i = threadIdx.x; i < NBK; i += 256) h[i] = 0;
    __syncthreads();
    for (int e = base + threadIdx.x; e < end; e += 256) {
        int d = dst[e];
        int s = src[e];
        int b = d >> BSHIFT;
        int p = atomicAdd(&h[b], 1);
        rec[rb[b] + p] = (unsigned)s | ((unsigned)(d & 255) << 16);
    }
}

// ---------------- pass D: per-bucket finalize (deg/dinv/offs + in-place src sort) ----------------

__global__ __launch_bounds__(256) void bucket_finalize(const int* __restrict__ baseS,
                                                       const int* __restrict__ baseD,
                                                       unsigned* __restrict__ recS,
                                                       unsigned* __restrict__ recD,
                                                       int* __restrict__ offsS,
                                                       int* __restrict__ offsD,
                                                       float* __restrict__ dinvS,
                                                       float* __restrict__ dinvD) {
    __shared__ unsigned recs[CAP];
    __shared__ int lc[256], sA[256], sB[256];
    int rel = blockIdx.y;
    const int* base = rel ? baseD : baseS;
    unsigned* rec = rel ? recD : recS;
    int* offs = rel ? offsD : offsS;
    float* dinv = rel ? dinvD : dinvS;
    int b = blockIdx.x;
    int b0 = base[b], b1 = base[b + 1];
    int cnt = b1 - b0;
    int t = threadIdx.x;
    lc[t] = 0;
    __syncthreads();
    for (int i = t; i < cnt; i += 256) {
        unsigned r = rec[b0 + i];
        if (i < CAP) recs[i] = r;
        atomicAdd(&lc[r >> 16], 1);
    }
    __syncthreads();
    int v = lc[t];
    int g = (b << BSHIFT) + t;
    if (g < NN) dinv[g] = rsqrtf((float)v + 1.0f);  // in-degree + self loop
    sA[t] = v;
    __syncthreads();
    int* pin = sA; int* pout = sB;
    for (int st = 1; st < 256; st <<= 1) {
        int x = pin[t];
        if (t >= st) x += pin[t - st];
        pout[t] = x;
        __syncthreads();
        int* tmp = pin; pin = pout; pout = tmp;
    }
    int excl = pin[t] - v;
    if (g < NN) offs[g] = b0 + excl;
    lc[t] = excl;  // reuse as cursor
    __syncthreads();
    for (int i = t; i < cnt; i += 256) {
        unsigned r = (i < CAP) ? recs[i] : rec[b0 + i];
        int p = atomicAdd(&lc[r >> 16], 1);
        rec[b0 + p] = r & 0xFFFFu;
    }
}

// ---------------- dual GEMM with dinv pre-scale epilogue ----------------

__global__ __launch_bounds__(256) void gemm_dual(const float* __restrict__ X,
                                                 const float* __restrict__ Wa,
                                                 const float* __restrict__ Wb,
                                                 const float* __restrict__ dinvA,
                                                 const float* __restrict__ dinvB,
                                                 float* __restrict__ Ya,
                                                 float* __restrict__ Yb, int n) {
    int row = blockIdx.x * 256 + threadIdx.x;
    if (row >= n) return;
    float xr[64];
    const float4* xv = reinterpret_cast<const float4*>(X + (size_t)row * 64);
#pragma unroll
    for (int q = 0; q < 16; q++) {
        float4 t = xv[q];
        xr[4 * q + 0] = t.x; xr[4 * q + 1] = t.y;
        xr[4 * q + 2] = t.z; xr[4 * q + 3] = t.w;
    }
#pragma unroll
    for (int r = 0; r < 2; r++) {
        const float* __restrict__ W = (r == 0) ? Wa : Wb;
        float sc = (r == 0) ? dinvA[row] : dinvB[row];
        float* __restrict__ Y = ((r == 0) ? Ya : Yb) + (size_t)row * 64;
        for (int jt = 0; jt < 4; jt++) {
            float acc[16];
#pragma unroll
            for (int j = 0; j < 16; j++) acc[j] = 0.0f;
#pragma unroll 8
            for (int k = 0; k < 64; k++) {
                float xk = xr[k];
#pragma unroll
                for (int j = 0; j < 16; j++)
                    acc[j] = fmaf(xk, W[k * 64 + jt * 16 + j], acc[j]);
            }
            float4* yo = reinterpret_cast<float4*>(Y + jt * 16);
            yo[0] = make_float4(sc * acc[0], sc * acc[1], sc * acc[2], sc * acc[3]);
            yo[1] = make_float4(sc * acc[4], sc * acc[5], sc * acc[6], sc * acc[7]);
            yo[2] = make_float4(sc * acc[8], sc * acc[9], sc * acc[10], sc * acc[11]);
            yo[3] = make_float4(sc * acc[12], sc * acc[13], sc * acc[14], sc * acc[15]);
        }
    }
}

// ---------------- fused gather + combine (+ optional linear head) ----------------
// one wave per dst node, lane = feature index; 8+8 outstanding row loads.

template <int HEAD>
__global__ __launch_bounds__(256) void gather_fused(const int* __restrict__ offsS,
                                                    const int* __restrict__ srcS,
                                                    const int* __restrict__ offsD,
                                                    const int* __restrict__ srcD,
                                                    const float* __restrict__ hpS,
                                                    const float* __restrict__ hpD,
                                                    const float* __restrict__ dinvS,
                                                    const float* __restrict__ dinvD,
                                                    const float* __restrict__ ba,
                                                    const float* __restrict__ bb,
                                                    const float* __restrict__ Wlin,
                                                    const float* __restrict__ blin,
                                                    float* __restrict__ out, int n) {
    int wid = (blockIdx.x * 256 + threadIdx.x) >> 6;
    int lane = threadIdx.x & 63;
    if (wid >= n) return;

    int eS = offsS[wid], eS1 = offsS[wid + 1];
    int eD = offsD[wid], eD1 = offsD[wid + 1];
    float accS = hpS[(size_t)wid * 64 + lane];  // self loop
    float accD = hpD[(size_t)wid * 64 + lane];

    // steady state: 16 outstanding row loads (8 S + 8 D)
    while (eS + 8 <= eS1 && eD + 8 <= eD1) {
        int s0 = srcS[eS], s1 = srcS[eS + 1], s2 = srcS[eS + 2], s3 = srcS[eS + 3];
        int s4 = srcS[eS + 4], s5 = srcS[eS + 5], s6 = srcS[eS + 6], s7 = srcS[eS + 7];
        int d0 = srcD[eD], d1 = srcD[eD + 1], d2 = srcD[eD + 2], d3 = srcD[eD + 3];
        int d4 = srcD[eD + 4], d5 = srcD[eD + 5], d6 = srcD[eD + 6], d7 = srcD[eD + 7];
        float a0 = hpS[(size_t)s0 * 64 + lane];
        float a1 = hpS[(size_t)s1 * 64 + lane];
        float a2 = hpS[(size_t)s2 * 64 + lane];
        float a3 = hpS[(size_t)s3 * 64 + lane];
        float a4 = hpS[(size_t)s4 * 64 + lane];
        float a5 = hpS[(size_t)s5 * 64 + lane];
        float a6 = hpS[(size_t)s6 * 64 + lane];
        float a7 = hpS[(size_t)s7 * 64 + lane];
        float b0 = hpD[(size_t)d0 * 64 + lane];
        float b1 = hpD[(size_t)d1 * 64 + lane];
        float b2 = hpD[(size_t)d2 * 64 + lane];
        float b3 = hpD[(size_t)d3 * 64 + lane];
        float b4 = hpD[(size_t)d4 * 64 + lane];
        float b5 = hpD[(size_t)d5 * 64 + lane];
        float b6 = hpD[(size_t)d6 * 64 + lane];
        float b7 = hpD[(size_t)d7 * 64 + lane];
        accS += ((a0 + a1) + (a2 + a3)) + ((a4 + a5) + (a6 + a7));
        accD += ((b0 + b1) + (b2 + b3)) + ((b4 + b5) + (b6 + b7));
        eS += 8; eD += 8;
    }
    // drain S
    while (eS + 4 <= eS1) {
        int s0 = srcS[eS], s1 = srcS[eS + 1], s2 = srcS[eS + 2], s3 = srcS[eS + 3];
        float a0 = hpS[(size_t)s0 * 64 + lane];
        float a1 = hpS[(size_t)s1 * 64 + lane];
        float a2 = hpS[(size_t)s2 * 64 + lane];
        float a3 = hpS[(size_t)s3 * 64 + lane];
        accS += (a0 + a1) + (a2 + a3);
        eS += 4;
    }
    while (eS < eS1) accS += hpS[(size_t)srcS[eS++] * 64 + lane];
    // drain D
    while (eD + 4 <= eD1) {
        int d0 = srcD[eD], d1 = srcD[eD + 1], d2 = srcD[eD + 2], d3 = srcD[eD + 3];
        float b0 = hpD[(size_t)d0 * 64 + lane];
        float b1 = hpD[(size_t)d1 * 64 + lane];
        float b2 = hpD[(size_t)d2 * 64 + lane];
        float b3 = hpD[(size_t)d3 * 64 + lane];
        accD += (b0 + b1) + (b2 + b3);
        eD += 4;
    }
    while (eD < eD1) accD += hpD[(size_t)srcD[eD++] * 64 + lane];

    float v = dinvS[wid] * accS + dinvD[wid] * accD + ba[lane] + bb[lane];
    v = fmaxf(v, 0.0f);

    if (HEAD == 0) {
        out[(size_t)wid * 64 + lane] = v;
    } else {
#pragma unroll
        for (int j = 0; j < 3; j++) {
            float p = v * Wlin[lane * 3 + j];
#pragma unroll
            for (int st = 32; st >= 1; st >>= 1) p += __shfl_xor(p, st, 64);
            if (lane == 0) out[(size_t)wid * 3 + j] = p + blin[j];
        }
    }
}

extern "C" void kernel_launch(void* const* d_in, const int* in_sizes, int n_in,
                              void* d_out, int out_size, void* d_ws, size_t ws_size,
                              hipStream_t stream) {
    const float* x    = (const float*)d_in[0];
    const int*   eis  = (const int*)d_in[1];
    const int*   eid  = (const int*)d_in[2];
    const float* W1s  = (const float*)d_in[3];
    const float* b1s  = (const float*)d_in[4];
    const float* W1d  = (const float*)d_in[5];
    const float* b1d  = (const float*)d_in[6];
    const float* W2s  = (const float*)d_in[7];
    const float* b2s  = (const float*)d_in[8];
    const float* W2d  = (const float*)d_in[9];
    const float* b2d  = (const float*)d_in[10];
    const float* Wlin = (const float*)d_in[11];
    const float* blin = (const float*)d_in[12];

    const int N  = NN;
    const int Es = in_sizes[1] / 2;
    const int Ed = in_sizes[2] / 2;
    int Emax = (Es > Ed) ? Es : Ed;

    // workspace layout (4B elements)
    int*   cntS  = (int*)d_ws;                 // [NBK]
    int*   cntD  = cntS + NBK;                 // [NBK]
    int*   baseS = cntD + NBK;                 // [NBK+1]
    int*   baseD = baseS + (NBK + 1);          // [NBK+1]
    int*   curS  = baseD + (NBK + 1);          // [NBK]
    int*   curD  = curS + NBK;                 // [NBK]
    int*   offsS = curD + NBK;                 // [N+4]
    int*   offsD = offsS + (N + 4);            // [N+4]
    float* dinvS = (float*)(offsD + (N + 4));  // [N]
    float* dinvD = dinvS + N;                  // [N]
    unsigned* recS = (unsigned*)(dinvD + N);   // [Es] records, then final src ids
    unsigned* recD = recS + Es;                // [Ed]
    float* bufA  = (float*)(recD + Ed);        // [N*64]
    float* bufB  = bufA + (size_t)N * 64;      // [N*64]
    float* bufH  = bufB + (size_t)N * 64;      // [N*64]

    // ---- CSR build (bucketed counting sort, reused by both layers) ----
    hipMemsetAsync(cntS, 0, (size_t)2 * NBK * sizeof(int), stream);
    dim3 egrid((Emax + CHUNK - 1) / CHUNK, 2);
    bucket_count<<<egrid, 256, 0, stream>>>(eis, Es, eid, Ed, cntS, cntD);
    bucket_scan<<<2, 256, 0, stream>>>(cntS, cntD, baseS, baseD, curS, curD, offsS, offsD);
    bucket_scatter<<<egrid, 256, 0, stream>>>(eis, Es, eid, Ed, curS, curD, recS, recD);
    dim3 fgrid(NBK, 2);
    bucket_finalize<<<fgrid, 256, 0, stream>>>(baseS, baseD, recS, recD, offsS, offsD,
                                               dinvS, dinvD);

    int gatherBlocks = (N * 64 + 255) / 256;
    const int* srcS = (const int*)recS;
    const int* srcD = (const int*)recD;

    // ---- layer 1 ----
    gemm_dual<<<(N + 255) / 256, 256, 0, stream>>>(x, W1s, W1d, dinvS, dinvD, bufA, bufB, N);
    gather_fused<0><<<gatherBlocks, 256, 0, stream>>>(offsS, srcS, offsD, srcD, bufA, bufB,
                                                      dinvS, dinvD, b1s, b1d, nullptr, nullptr,
                                                      bufH, N);

    // ---- layer 2 (head fused: writes out[N,3] directly) ----
    gemm_dual<<<(N + 255) / 256, 256, 0, stream>>>(bufH, W2s, W2d, dinvS, dinvD, bufA, bufB, N);
    gather_fused<1><<<gatherBlocks, 256, 0, stream>>>(offsS, srcS, offsD, srcD, bufA, bufB,
                                                      dinvS, dinvD, b2s, b2d, Wlin, blin,
                                                      (float*)d_out, N);
}

// Round 5
// 335.241 us; speedup vs baseline: 2.7592x; 1.0205x over previous
//
#include <hip/hip_runtime.h>
#include <hip/hip_fp16.h>

#define NN 50000
#define BSHIFT 8
#define NBK ((NN + 255) >> 8)   // 196 buckets of 256 nodes
#define CHUNK 4096
#define CAP 8192                 // per-bucket record capacity (mean ~4096, +64 sigma)

__device__ __forceinline__ float recw(unsigned r) {
    unsigned short us = (unsigned short)(r >> 16);
    __half h;
    __builtin_memcpy(&h, &us, 2);
    return __half2float(h);
}
__device__ __forceinline__ float2 h2f2(unsigned v) {
    __half2 h;
    __builtin_memcpy(&h, &v, 4);
    return __half22float2(h);
}
__device__ __forceinline__ unsigned f2h2(float a, float b) {
    __half2 h = __floats2half2_rn(a, b);
    unsigned u;
    __builtin_memcpy(&u, &h, 4);
    return u;
}

// ---------------- x -> fp16 convert ----------------

__global__ __launch_bounds__(256) void cvt_x(const float* __restrict__ x,
                                             unsigned* __restrict__ x16, int total4) {
    int i = blockIdx.x * 256 + threadIdx.x;  // over float4 groups
    if (i >= total4) return;
    float4 v = reinterpret_cast<const float4*>(x)[i];
    uint2 o;
    o.x = f2h2(v.x, v.y);
    o.y = f2h2(v.z, v.w);
    reinterpret_cast<uint2*>(x16)[i] = o;
}

// ---------------- pass A: per-bucket edge counts ----------------

__global__ __launch_bounds__(256) void bucket_count(const int* __restrict__ eiS, int Es,
                                                    const int* __restrict__ eiD, int Ed,
                                                    int* __restrict__ cntS,
                                                    int* __restrict__ cntD) {
    __shared__ int h[NBK];
    int rel = blockIdx.y;
    const int* dst = rel ? (eiD + Ed) : (eiS + Es);
    int E = rel ? Ed : Es;
    int* cnt = rel ? cntD : cntS;
    int base = blockIdx.x * CHUNK;
    if (base >= E) return;
    for (int i = threadIdx.x; i < NBK; i += 256) h[i] = 0;
    __syncthreads();
    int end = (base + CHUNK < E) ? base + CHUNK : E;
    for (int e = base + threadIdx.x; e < end; e += 256)
        atomicAdd(&h[dst[e] >> BSHIFT], 1);
    __syncthreads();
    for (int i = threadIdx.x; i < NBK; i += 256)
        if (h[i]) atomicAdd(&cnt[i], h[i]);
}

// ---------------- pass B: scan bucket counts ----------------

__global__ __launch_bounds__(256) void bucket_scan(const int* __restrict__ cntS,
                                                   const int* __restrict__ cntD,
                                                   int* __restrict__ baseS,
                                                   int* __restrict__ baseD,
                                                   int* __restrict__ curS,
                                                   int* __restrict__ curD,
                                                   int* __restrict__ offsS,
                                                   int* __restrict__ offsD) {
    __shared__ int sA[256], sB[256];
    const int* cnt = blockIdx.x ? cntD : cntS;
    int* base = blockIdx.x ? baseD : baseS;
    int* cur  = blockIdx.x ? curD : curS;
    int* offs = blockIdx.x ? offsD : offsS;
    int t = threadIdx.x;
    int v = (t < NBK) ? cnt[t] : 0;
    sA[t] = v;
    __syncthreads();
    int* pin = sA; int* pout = sB;
    for (int st = 1; st < 256; st <<= 1) {
        int x = pin[t];
        if (t >= st) x += pin[t - st];
        pout[t] = x;
        __syncthreads();
        int* tmp = pin; pin = pout; pout = tmp;
    }
    int incl = pin[t];
    int excl = incl - v;
    if (t < NBK) { base[t] = excl; cur[t] = excl; }
    if (t == NBK - 1) { base[NBK] = incl; offs[NN] = incl; }
}

// ---------------- pass C: scatter packed records ----------------

__global__ __launch_bounds__(256) void bucket_scatter(const int* __restrict__ eiS, int Es,
                                                      const int* __restrict__ eiD, int Ed,
                                                      int* __restrict__ curS,
                                                      int* __restrict__ curD,
                                                      unsigned* __restrict__ recS,
                                                      unsigned* __restrict__ recD) {
    __shared__ int h[NBK];
    __shared__ int rb[NBK];
    int rel = blockIdx.y;
    const int* ei = rel ? eiD : eiS;
    int E = rel ? Ed : Es;
    int* cur = rel ? curD : curS;
    unsigned* rec = rel ? recD : recS;
    int base = blockIdx.x * CHUNK;
    if (base >= E) return;
    const int* src = ei;
    const int* dst = ei + E;
    int end = (base + CHUNK < E) ? base + CHUNK : E;

    for (int i = threadIdx.x; i < NBK; i += 256) h[i] = 0;
    __syncthreads();
    for (int e = base + threadIdx.x; e < end; e += 256)
        atomicAdd(&h[dst[e] >> BSHIFT], 1);
    __syncthreads();
    for (int i = threadIdx.x; i < NBK; i += 256) {
        int c = h[i];
        rb[i] = c ? atomicAdd(&cur[i], c) : 0;
    }
    __syncthreads();
    for (int i = threadIdx.x; i < NBK; i += 256) h[i] = 0;
    __syncthreads();
    for (int e = base + threadIdx.x; e < end; e += 256) {
        int d = dst[e];
        int s = src[e];
        int b = d >> BSHIFT;
        int p = atomicAdd(&h[b], 1);
        rec[rb[b] + p] = (unsigned)s | ((unsigned)(d & 255) << 16);
    }
}

// ---------------- pass D: per-bucket finalize ----------------

__global__ __launch_bounds__(256) void bucket_finalize(const int* __restrict__ baseS,
                                                       const int* __restrict__ baseD,
                                                       unsigned* __restrict__ recS,
                                                       unsigned* __restrict__ recD,
                                                       int* __restrict__ offsS,
                                                       int* __restrict__ offsD,
                                                       float* __restrict__ dinvS,
                                                       float* __restrict__ dinvD) {
    __shared__ unsigned recs[CAP];
    __shared__ int lc[256], sA[256], sB[256];
    int rel = blockIdx.y;
    const int* base = rel ? baseD : baseS;
    unsigned* rec = rel ? recD : recS;
    int* offs = rel ? offsD : offsS;
    float* dinv = rel ? dinvD : dinvS;
    int b = blockIdx.x;
    int b0 = base[b], b1 = base[b + 1];
    int cnt = b1 - b0;
    int t = threadIdx.x;
    lc[t] = 0;
    __syncthreads();
    for (int i = t; i < cnt; i += 256) {
        unsigned r = rec[b0 + i];
        if (i < CAP) recs[i] = r;
        atomicAdd(&lc[r >> 16], 1);
    }
    __syncthreads();
    int v = lc[t];
    int g = (b << BSHIFT) + t;
    if (g < NN) dinv[g] = rsqrtf((float)v + 1.0f);
    sA[t] = v;
    __syncthreads();
    int* pin = sA; int* pout = sB;
    for (int st = 1; st < 256; st <<= 1) {
        int x = pin[t];
        if (t >= st) x += pin[t - st];
        pout[t] = x;
        __syncthreads();
        int* tmp = pin; pin = pout; pout = tmp;
    }
    int excl = pin[t] - v;
    if (g < NN) offs[g] = b0 + excl;
    lc[t] = excl;
    __syncthreads();
    for (int i = t; i < cnt; i += 256) {
        unsigned r = (i < CAP) ? recs[i] : rec[b0 + i];
        int p = atomicAdd(&lc[r >> 16], 1);
        rec[b0 + p] = r & 0xFFFFu;
    }
}

// ---------------- pack: rec = src | half(dinv[src])<<16 ----------------

__global__ __launch_bounds__(256) void pack_rec(unsigned* __restrict__ recS, int Es,
                                                unsigned* __restrict__ recD, int Ed,
                                                const float* __restrict__ dinvS,
                                                const float* __restrict__ dinvD) {
    int i = blockIdx.x * 256 + threadIdx.x;
    if (i < Es) {
        unsigned s = recS[i] & 0xFFFFu;
        __half h = __float2half(dinvS[s]);
        unsigned short us;
        __builtin_memcpy(&us, &h, 2);
        recS[i] = s | ((unsigned)us << 16);
    }
    if (i < Ed) {
        unsigned s = recD[i] & 0xFFFFu;
        __half h = __float2half(dinvD[s]);
        unsigned short us;
        __builtin_memcpy(&us, &h, 2);
        recD[i] = s | ((unsigned)us << 16);
    }
}

// ---------------- gather both relations from ONE fp16 feature buffer ----------------
// one wave per dst node; 32 lanes per row (half2/lane); 2 rows per load instruction.
// aggS[d] = dinvS[d] * (dinvS[d]*feat[d] + sum dinvS[s]*feat[s]),  same for D.

__global__ __launch_bounds__(256) void gather_agg(const int* __restrict__ offsS,
                                                  const unsigned* __restrict__ recS,
                                                  const int* __restrict__ offsD,
                                                  const unsigned* __restrict__ recD,
                                                  const unsigned* __restrict__ feat,
                                                  const float* __restrict__ dinvS,
                                                  const float* __restrict__ dinvD,
                                                  float2* __restrict__ aggS,
                                                  float2* __restrict__ aggD, int n) {
    int wid = (blockIdx.x * 256 + threadIdx.x) >> 6;
    int lane = threadIdx.x & 63;
    if (wid >= n) return;
    int grp = lane >> 5;
    int col = lane & 31;

    float dS = dinvS[wid];
    float dD = dinvD[wid];

    // self loop (group 0 only)
    unsigned selfv = feat[(size_t)wid * 32 + col];
    float2 sf = h2f2(selfv);
    float ws0 = grp ? 0.0f : dS;
    float wd0 = grp ? 0.0f : dD;
    float2 accS = make_float2(ws0 * sf.x, ws0 * sf.y);
    float2 accD = make_float2(wd0 * sf.x, wd0 * sf.y);

    int eS = offsS[wid], eS1 = offsS[wid + 1];
    int eD = offsD[wid], eD1 = offsD[wid + 1];

    // steady state: 4 S-pairs + 4 D-pairs = 8 row-pair loads in flight
    while (eS + 8 <= eS1 && eD + 8 <= eD1) {
        unsigned rs0 = recS[eS + 0 + grp], rs1 = recS[eS + 2 + grp];
        unsigned rs2 = recS[eS + 4 + grp], rs3 = recS[eS + 6 + grp];
        unsigned rd0 = recD[eD + 0 + grp], rd1 = recD[eD + 2 + grp];
        unsigned rd2 = recD[eD + 4 + grp], rd3 = recD[eD + 6 + grp];
        unsigned vs0 = feat[(size_t)(rs0 & 0xFFFFu) * 32 + col];
        unsigned vs1 = feat[(size_t)(rs1 & 0xFFFFu) * 32 + col];
        unsigned vs2 = feat[(size_t)(rs2 & 0xFFFFu) * 32 + col];
        unsigned vs3 = feat[(size_t)(rs3 & 0xFFFFu) * 32 + col];
        unsigned vd0 = feat[(size_t)(rd0 & 0xFFFFu) * 32 + col];
        unsigned vd1 = feat[(size_t)(rd1 & 0xFFFFu) * 32 + col];
        unsigned vd2 = feat[(size_t)(rd2 & 0xFFFFu) * 32 + col];
        unsigned vd3 = feat[(size_t)(rd3 & 0xFFFFu) * 32 + col];
        float w; float2 f;
        w = recw(rs0); f = h2f2(vs0); accS.x = fmaf(w, f.x, accS.x); accS.y = fmaf(w, f.y, accS.y);
        w = recw(rs1); f = h2f2(vs1); accS.x = fmaf(w, f.x, accS.x); accS.y = fmaf(w, f.y, accS.y);
        w = recw(rs2); f = h2f2(vs2); accS.x = fmaf(w, f.x, accS.x); accS.y = fmaf(w, f.y, accS.y);
        w = recw(rs3); f = h2f2(vs3); accS.x = fmaf(w, f.x, accS.x); accS.y = fmaf(w, f.y, accS.y);
        w = recw(rd0); f = h2f2(vd0); accD.x = fmaf(w, f.x, accD.x); accD.y = fmaf(w, f.y, accD.y);
        w = recw(rd1); f = h2f2(vd1); accD.x = fmaf(w, f.x, accD.x); accD.y = fmaf(w, f.y, accD.y);
        w = recw(rd2); f = h2f2(vd2); accD.x = fmaf(w, f.x, accD.x); accD.y = fmaf(w, f.y, accD.y);
        w = recw(rd3); f = h2f2(vd3); accD.x = fmaf(w, f.x, accD.x); accD.y = fmaf(w, f.y, accD.y);
        eS += 8; eD += 8;
    }
    // drain S pairs
    while (eS + 2 <= eS1) {
        unsigned r = recS[eS + grp];
        unsigned v = feat[(size_t)(r & 0xFFFFu) * 32 + col];
        float w = recw(r); float2 f = h2f2(v);
        accS.x = fmaf(w, f.x, accS.x); accS.y = fmaf(w, f.y, accS.y);
        eS += 2;
    }
    if (eS < eS1) {  // single leftover: group 1 contributes 0
        unsigned r = recS[eS];
        unsigned v = feat[(size_t)(r & 0xFFFFu) * 32 + col];
        float w = grp ? 0.0f : recw(r); float2 f = h2f2(v);
        accS.x = fmaf(w, f.x, accS.x); accS.y = fmaf(w, f.y, accS.y);
    }
    // drain D pairs
    while (eD + 2 <= eD1) {
        unsigned r = recD[eD + grp];
        unsigned v = feat[(size_t)(r & 0xFFFFu) * 32 + col];
        float w = recw(r); float2 f = h2f2(v);
        accD.x = fmaf(w, f.x, accD.x); accD.y = fmaf(w, f.y, accD.y);
        eD += 2;
    }
    if (eD < eD1) {
        unsigned r = recD[eD];
        unsigned v = feat[(size_t)(r & 0xFFFFu) * 32 + col];
        float w = grp ? 0.0f : recw(r); float2 f = h2f2(v);
        accD.x = fmaf(w, f.x, accD.x); accD.y = fmaf(w, f.y, accD.y);
    }

    // fold groups, scale by dst dinv, store (group 0 lanes)
    accS.x += __shfl_xor(accS.x, 32, 64);
    accS.y += __shfl_xor(accS.y, 32, 64);
    accD.x += __shfl_xor(accD.x, 32, 64);
    accD.y += __shfl_xor(accD.y, 32, 64);
    if (grp == 0) {
        aggS[(size_t)wid * 32 + col] = make_float2(dS * accS.x, dS * accS.y);
        aggD[(size_t)wid * 32 + col] = make_float2(dD * accD.x, dD * accD.y);
    }
}

// ---------------- apply: h = relu(aggS@Wa + aggD@Wb + ba + bb) [+ head] ----------------

template <int HEAD>
__global__ __launch_bounds__(256) void apply_k(const float2* __restrict__ aggSp,
                                               const float2* __restrict__ aggDp,
                                               const float* __restrict__ Wa,
                                               const float* __restrict__ Wb,
                                               const float* __restrict__ ba,
                                               const float* __restrict__ bb,
                                               const float* __restrict__ Wlin,
                                               const float* __restrict__ blin,
                                               unsigned* __restrict__ outH,
                                               float* __restrict__ out3, int n) {
    int row = blockIdx.x * 256 + threadIdx.x;
    if (row >= n) return;
    float as[64], ad[64];
    const float4* pS = reinterpret_cast<const float4*>(aggSp + (size_t)row * 32);
    const float4* pD = reinterpret_cast<const float4*>(aggDp + (size_t)row * 32);
#pragma unroll
    for (int q = 0; q < 16; q++) {
        float4 t = pS[q];
        as[4 * q + 0] = t.x; as[4 * q + 1] = t.y; as[4 * q + 2] = t.z; as[4 * q + 3] = t.w;
        float4 u = pD[q];
        ad[4 * q + 0] = u.x; ad[4 * q + 1] = u.y; ad[4 * q + 2] = u.z; ad[4 * q + 3] = u.w;
    }
    float h0 = 0.0f, h1 = 0.0f, h2 = 0.0f;
    for (int jt = 0; jt < 4; jt++) {
        float acc[16];
#pragma unroll
        for (int j = 0; j < 16; j++) acc[j] = ba[jt * 16 + j] + bb[jt * 16 + j];
#pragma unroll 8
        for (int k = 0; k < 64; k++) {
            float a1 = as[k], a2 = ad[k];
#pragma unroll
            for (int j = 0; j < 16; j++)
                acc[j] = fmaf(a1, Wa[k * 64 + jt * 16 + j],
                         fmaf(a2, Wb[k * 64 + jt * 16 + j], acc[j]));
        }
        if (HEAD == 0) {
            unsigned u[8];
#pragma unroll
            for (int p = 0; p < 8; p++)
                u[p] = f2h2(fmaxf(acc[2 * p], 0.0f), fmaxf(acc[2 * p + 1], 0.0f));
            uint4* o = reinterpret_cast<uint4*>(outH + (size_t)row * 32 + jt * 8);
            o[0] = make_uint4(u[0], u[1], u[2], u[3]);
            o[1] = make_uint4(u[4], u[5], u[6], u[7]);
        } else {
#pragma unroll
            for (int j = 0; j < 16; j++) {
                float v = fmaxf(acc[j], 0.0f);
                int f = jt * 16 + j;
                h0 = fmaf(v, Wlin[f * 3 + 0], h0);
                h1 = fmaf(v, Wlin[f * 3 + 1], h1);
                h2 = fmaf(v, Wlin[f * 3 + 2], h2);
            }
        }
    }
    if (HEAD == 1) {
        out3[row * 3 + 0] = h0 + blin[0];
        out3[row * 3 + 1] = h1 + blin[1];
        out3[row * 3 + 2] = h2 + blin[2];
    }
}

extern "C" void kernel_launch(void* const* d_in, const int* in_sizes, int n_in,
                              void* d_out, int out_size, void* d_ws, size_t ws_size,
                              hipStream_t stream) {
    const float* x    = (const float*)d_in[0];
    const int*   eis  = (const int*)d_in[1];
    const int*   eid  = (const int*)d_in[2];
    const float* W1s  = (const float*)d_in[3];
    const float* b1s  = (const float*)d_in[4];
    const float* W1d  = (const float*)d_in[5];
    const float* b1d  = (const float*)d_in[6];
    const float* W2s  = (const float*)d_in[7];
    const float* b2s  = (const float*)d_in[8];
    const float* W2d  = (const float*)d_in[9];
    const float* b2d  = (const float*)d_in[10];
    const float* Wlin = (const float*)d_in[11];
    const float* blin = (const float*)d_in[12];

    const int N  = NN;
    const int Es = in_sizes[1] / 2;
    const int Ed = in_sizes[2] / 2;
    int Emax = (Es > Ed) ? Es : Ed;

    // workspace layout (4B elements)
    int*   cntS  = (int*)d_ws;
    int*   cntD  = cntS + NBK;
    int*   baseS = cntD + NBK;
    int*   baseD = baseS + (NBK + 1);
    int*   curS  = baseD + (NBK + 1);
    int*   curD  = curS + NBK;
    int*   offsS = curD + NBK;                  // [N+4]
    int*   offsD = offsS + (N + 4);             // [N+4]
    float* dinvS = (float*)(offsD + (N + 4));   // [N]
    float* dinvD = dinvS + N;                   // [N]
    unsigned* recS = (unsigned*)(dinvD + N);    // [Es]
    unsigned* recD = recS + Es;                 // [Ed]
    unsigned* x16  = recD + Ed;                 // [N*32] fp16 features
    unsigned* h16  = x16 + (size_t)N * 32;      // [N*32] fp16 layer-1 output
    float2* aggS = (float2*)(h16 + (size_t)N * 32);  // [N*32] float2
    float2* aggD = aggS + (size_t)N * 32;            // [N*32] float2

    // ---- feature convert + CSR build ----
    hipMemsetAsync(cntS, 0, (size_t)2 * NBK * sizeof(int), stream);
    cvt_x<<<(N * 16 + 255) / 256, 256, 0, stream>>>(x, x16, N * 16);
    dim3 egrid((Emax + CHUNK - 1) / CHUNK, 2);
    bucket_count<<<egrid, 256, 0, stream>>>(eis, Es, eid, Ed, cntS, cntD);
    bucket_scan<<<2, 256, 0, stream>>>(cntS, cntD, baseS, baseD, curS, curD, offsS, offsD);
    bucket_scatter<<<egrid, 256, 0, stream>>>(eis, Es, eid, Ed, curS, curD, recS, recD);
    dim3 fgrid(NBK, 2);
    bucket_finalize<<<fgrid, 256, 0, stream>>>(baseS, baseD, recS, recD, offsS, offsD,
                                               dinvS, dinvD);
    pack_rec<<<(Emax + 255) / 256, 256, 0, stream>>>(recS, Es, recD, Ed, dinvS, dinvD);

    int gatherBlocks = (N * 64 + 255) / 256;
    int applyBlocks = (N + 255) / 256;

    // ---- layer 1: aggregate x, then apply W ----
    gather_agg<<<gatherBlocks, 256, 0, stream>>>(offsS, recS, offsD, recD, x16,
                                                 dinvS, dinvD, aggS, aggD, N);
    apply_k<0><<<applyBlocks, 256, 0, stream>>>(aggS, aggD, W1s, W1d, b1s, b1d,
                                                nullptr, nullptr, h16, nullptr, N);

    // ---- layer 2: aggregate h1, then apply W + head ----
    gather_agg<<<gatherBlocks, 256, 0, stream>>>(offsS, recS, offsD, recD, h16,
                                                 dinvS, dinvD, aggS, aggD, N);
    apply_k<1><<<applyBlocks, 256, 0, stream>>>(aggS, aggD, W2s, W2d, b2s, b2d,
                                                Wlin, blin, nullptr, (float*)d_out, N);
}

// Round 6
// 298.063 us; speedup vs baseline: 3.1034x; 1.1247x over previous
//
#include <hip/hip_runtime.h>
#include <hip/hip_fp16.h>

#define NN 50000
#define BSHIFT 8
#define NBK ((NN + 255) >> 8)   // 196 buckets of 256 nodes
#define CHUNK 4096
#define CAP 8192                 // per-bucket record capacity (mean ~4096, +64 sigma)

__device__ __forceinline__ float recw(unsigned r) {
    unsigned short us = (unsigned short)(r >> 16);
    __half h;
    __builtin_memcpy(&h, &us, 2);
    return __half2float(h);
}
__device__ __forceinline__ float2 h2f2(unsigned v) {
    __half2 h;
    __builtin_memcpy(&h, &v, 4);
    return __half22float2(h);
}
__device__ __forceinline__ unsigned f2h2(float a, float b) {
    __half2 h = __floats2half2_rn(a, b);
    unsigned u;
    __builtin_memcpy(&u, &h, 4);
    return u;
}

// ---------------- x -> fp16 convert ----------------

__global__ __launch_bounds__(256) void cvt_x(const float* __restrict__ x,
                                             unsigned* __restrict__ x16, int total4) {
    int i = blockIdx.x * 256 + threadIdx.x;  // over float4 groups
    if (i >= total4) return;
    float4 v = reinterpret_cast<const float4*>(x)[i];
    uint2 o;
    o.x = f2h2(v.x, v.y);
    o.y = f2h2(v.z, v.w);
    reinterpret_cast<uint2*>(x16)[i] = o;
}

// ---------------- pass A: per-bucket edge counts ----------------

__global__ __launch_bounds__(256) void bucket_count(const int* __restrict__ eiS, int Es,
                                                    const int* __restrict__ eiD, int Ed,
                                                    int* __restrict__ cntS,
                                                    int* __restrict__ cntD) {
    __shared__ int h[NBK];
    int rel = blockIdx.y;
    const int* dst = rel ? (eiD + Ed) : (eiS + Es);
    int E = rel ? Ed : Es;
    int* cnt = rel ? cntD : cntS;
    int base = blockIdx.x * CHUNK;
    if (base >= E) return;
    for (int i = threadIdx.x; i < NBK; i += 256) h[i] = 0;
    __syncthreads();
    int end = (base + CHUNK < E) ? base + CHUNK : E;
    for (int e = base + threadIdx.x; e < end; e += 256)
        atomicAdd(&h[dst[e] >> BSHIFT], 1);
    __syncthreads();
    for (int i = threadIdx.x; i < NBK; i += 256)
        if (h[i]) atomicAdd(&cnt[i], h[i]);
}

// ---------------- pass B: scan bucket counts ----------------

__global__ __launch_bounds__(256) void bucket_scan(const int* __restrict__ cntS,
                                                   const int* __restrict__ cntD,
                                                   int* __restrict__ baseS,
                                                   int* __restrict__ baseD,
                                                   int* __restrict__ curS,
                                                   int* __restrict__ curD,
                                                   int* __restrict__ offsS,
                                                   int* __restrict__ offsD) {
    __shared__ int sA[256], sB[256];
    const int* cnt = blockIdx.x ? cntD : cntS;
    int* base = blockIdx.x ? baseD : baseS;
    int* cur  = blockIdx.x ? curD : curS;
    int* offs = blockIdx.x ? offsD : offsS;
    int t = threadIdx.x;
    int v = (t < NBK) ? cnt[t] : 0;
    sA[t] = v;
    __syncthreads();
    int* pin = sA; int* pout = sB;
    for (int st = 1; st < 256; st <<= 1) {
        int x = pin[t];
        if (t >= st) x += pin[t - st];
        pout[t] = x;
        __syncthreads();
        int* tmp = pin; pin = pout; pout = tmp;
    }
    int incl = pin[t];
    int excl = incl - v;
    if (t < NBK) { base[t] = excl; cur[t] = excl; }
    if (t == NBK - 1) { base[NBK] = incl; offs[NN] = incl; }
}

// ---------------- pass C: scatter packed records ----------------

__global__ __launch_bounds__(256) void bucket_scatter(const int* __restrict__ eiS, int Es,
                                                      const int* __restrict__ eiD, int Ed,
                                                      int* __restrict__ curS,
                                                      int* __restrict__ curD,
                                                      unsigned* __restrict__ recS,
                                                      unsigned* __restrict__ recD) {
    __shared__ int h[NBK];
    __shared__ int rb[NBK];
    int rel = blockIdx.y;
    const int* ei = rel ? eiD : eiS;
    int E = rel ? Ed : Es;
    int* cur = rel ? curD : curS;
    unsigned* rec = rel ? recD : recS;
    int base = blockIdx.x * CHUNK;
    if (base >= E) return;
    const int* src = ei;
    const int* dst = ei + E;
    int end = (base + CHUNK < E) ? base + CHUNK : E;

    for (int i = threadIdx.x; i < NBK; i += 256) h[i] = 0;
    __syncthreads();
    for (int e = base + threadIdx.x; e < end; e += 256)
        atomicAdd(&h[dst[e] >> BSHIFT], 1);
    __syncthreads();
    for (int i = threadIdx.x; i < NBK; i += 256) {
        int c = h[i];
        rb[i] = c ? atomicAdd(&cur[i], c) : 0;
    }
    __syncthreads();
    for (int i = threadIdx.x; i < NBK; i += 256) h[i] = 0;
    __syncthreads();
    for (int e = base + threadIdx.x; e < end; e += 256) {
        int d = dst[e];
        int s = src[e];
        int b = d >> BSHIFT;
        int p = atomicAdd(&h[b], 1);
        rec[rb[b] + p] = (unsigned)s | ((unsigned)(d & 255) << 16);
    }
}

// ---------------- pass D: per-bucket finalize ----------------

__global__ __launch_bounds__(256) void bucket_finalize(const int* __restrict__ baseS,
                                                       const int* __restrict__ baseD,
                                                       unsigned* __restrict__ recS,
                                                       unsigned* __restrict__ recD,
                                                       int* __restrict__ offsS,
                                                       int* __restrict__ offsD,
                                                       float* __restrict__ dinvS,
                                                       float* __restrict__ dinvD) {
    __shared__ unsigned recs[CAP];
    __shared__ int lc[256], sA[256], sB[256];
    int rel = blockIdx.y;
    const int* base = rel ? baseD : baseS;
    unsigned* rec = rel ? recD : recS;
    int* offs = rel ? offsD : offsS;
    float* dinv = rel ? dinvD : dinvS;
    int b = blockIdx.x;
    int b0 = base[b], b1 = base[b + 1];
    int cnt = b1 - b0;
    int t = threadIdx.x;
    lc[t] = 0;
    __syncthreads();
    for (int i = t; i < cnt; i += 256) {
        unsigned r = rec[b0 + i];
        if (i < CAP) recs[i] = r;
        atomicAdd(&lc[r >> 16], 1);
    }
    __syncthreads();
    int v = lc[t];
    int g = (b << BSHIFT) + t;
    if (g < NN) dinv[g] = rsqrtf((float)v + 1.0f);
    sA[t] = v;
    __syncthreads();
    int* pin = sA; int* pout = sB;
    for (int st = 1; st < 256; st <<= 1) {
        int x = pin[t];
        if (t >= st) x += pin[t - st];
        pout[t] = x;
        __syncthreads();
        int* tmp = pin; pin = pout; pout = tmp;
    }
    int excl = pin[t] - v;
    if (g < NN) offs[g] = b0 + excl;
    lc[t] = excl;
    __syncthreads();
    for (int i = t; i < cnt; i += 256) {
        unsigned r = (i < CAP) ? recs[i] : rec[b0 + i];
        int p = atomicAdd(&lc[r >> 16], 1);
        rec[b0 + p] = r & 0xFFFFu;
    }
}

// ---------------- pack: rec = src | half(dinv[src])<<16 ----------------

__global__ __launch_bounds__(256) void pack_rec(unsigned* __restrict__ recS, int Es,
                                                unsigned* __restrict__ recD, int Ed,
                                                const float* __restrict__ dinvS,
                                                const float* __restrict__ dinvD) {
    int i = blockIdx.x * 256 + threadIdx.x;
    if (i < Es) {
        unsigned s = recS[i] & 0xFFFFu;
        __half h = __float2half(dinvS[s]);
        unsigned short us;
        __builtin_memcpy(&us, &h, 2);
        recS[i] = s | ((unsigned)us << 16);
    }
    if (i < Ed) {
        unsigned s = recD[i] & 0xFFFFu;
        __half h = __float2half(dinvD[s]);
        unsigned short us;
        __builtin_memcpy(&us, &h, 2);
        recD[i] = s | ((unsigned)us << 16);
    }
}

// ---------------- gather both relations from ONE fp16 feature buffer ----------------

__global__ __launch_bounds__(256) void gather_agg(const int* __restrict__ offsS,
                                                  const unsigned* __restrict__ recS,
                                                  const int* __restrict__ offsD,
                                                  const unsigned* __restrict__ recD,
                                                  const unsigned* __restrict__ feat,
                                                  const float* __restrict__ dinvS,
                                                  const float* __restrict__ dinvD,
                                                  float2* __restrict__ aggS,
                                                  float2* __restrict__ aggD, int n) {
    int wid = (blockIdx.x * 256 + threadIdx.x) >> 6;
    int lane = threadIdx.x & 63;
    if (wid >= n) return;
    int grp = lane >> 5;
    int col = lane & 31;

    float dS = dinvS[wid];
    float dD = dinvD[wid];

    unsigned selfv = feat[(size_t)wid * 32 + col];
    float2 sf = h2f2(selfv);
    float ws0 = grp ? 0.0f : dS;
    float wd0 = grp ? 0.0f : dD;
    float2 accS = make_float2(ws0 * sf.x, ws0 * sf.y);
    float2 accD = make_float2(wd0 * sf.x, wd0 * sf.y);

    int eS = offsS[wid], eS1 = offsS[wid + 1];
    int eD = offsD[wid], eD1 = offsD[wid + 1];

    while (eS + 8 <= eS1 && eD + 8 <= eD1) {
        unsigned rs0 = recS[eS + 0 + grp], rs1 = recS[eS + 2 + grp];
        unsigned rs2 = recS[eS + 4 + grp], rs3 = recS[eS + 6 + grp];
        unsigned rd0 = recD[eD + 0 + grp], rd1 = recD[eD + 2 + grp];
        unsigned rd2 = recD[eD + 4 + grp], rd3 = recD[eD + 6 + grp];
        unsigned vs0 = feat[(size_t)(rs0 & 0xFFFFu) * 32 + col];
        unsigned vs1 = feat[(size_t)(rs1 & 0xFFFFu) * 32 + col];
        unsigned vs2 = feat[(size_t)(rs2 & 0xFFFFu) * 32 + col];
        unsigned vs3 = feat[(size_t)(rs3 & 0xFFFFu) * 32 + col];
        unsigned vd0 = feat[(size_t)(rd0 & 0xFFFFu) * 32 + col];
        unsigned vd1 = feat[(size_t)(rd1 & 0xFFFFu) * 32 + col];
        unsigned vd2 = feat[(size_t)(rd2 & 0xFFFFu) * 32 + col];
        unsigned vd3 = feat[(size_t)(rd3 & 0xFFFFu) * 32 + col];
        float w; float2 f;
        w = recw(rs0); f = h2f2(vs0); accS.x = fmaf(w, f.x, accS.x); accS.y = fmaf(w, f.y, accS.y);
        w = recw(rs1); f = h2f2(vs1); accS.x = fmaf(w, f.x, accS.x); accS.y = fmaf(w, f.y, accS.y);
        w = recw(rs2); f = h2f2(vs2); accS.x = fmaf(w, f.x, accS.x); accS.y = fmaf(w, f.y, accS.y);
        w = recw(rs3); f = h2f2(vs3); accS.x = fmaf(w, f.x, accS.x); accS.y = fmaf(w, f.y, accS.y);
        w = recw(rd0); f = h2f2(vd0); accD.x = fmaf(w, f.x, accD.x); accD.y = fmaf(w, f.y, accD.y);
        w = recw(rd1); f = h2f2(vd1); accD.x = fmaf(w, f.x, accD.x); accD.y = fmaf(w, f.y, accD.y);
        w = recw(rd2); f = h2f2(vd2); accD.x = fmaf(w, f.x, accD.x); accD.y = fmaf(w, f.y, accD.y);
        w = recw(rd3); f = h2f2(vd3); accD.x = fmaf(w, f.x, accD.x); accD.y = fmaf(w, f.y, accD.y);
        eS += 8; eD += 8;
    }
    while (eS + 2 <= eS1) {
        unsigned r = recS[eS + grp];
        unsigned v = feat[(size_t)(r & 0xFFFFu) * 32 + col];
        float w = recw(r); float2 f = h2f2(v);
        accS.x = fmaf(w, f.x, accS.x); accS.y = fmaf(w, f.y, accS.y);
        eS += 2;
    }
    if (eS < eS1) {
        unsigned r = recS[eS];
        unsigned v = feat[(size_t)(r & 0xFFFFu) * 32 + col];
        float w = grp ? 0.0f : recw(r); float2 f = h2f2(v);
        accS.x = fmaf(w, f.x, accS.x); accS.y = fmaf(w, f.y, accS.y);
    }
    while (eD + 2 <= eD1) {
        unsigned r = recD[eD + grp];
        unsigned v = feat[(size_t)(r & 0xFFFFu) * 32 + col];
        float w = recw(r); float2 f = h2f2(v);
        accD.x = fmaf(w, f.x, accD.x); accD.y = fmaf(w, f.y, accD.y);
        eD += 2;
    }
    if (eD < eD1) {
        unsigned r = recD[eD];
        unsigned v = feat[(size_t)(r & 0xFFFFu) * 32 + col];
        float w = grp ? 0.0f : recw(r); float2 f = h2f2(v);
        accD.x = fmaf(w, f.x, accD.x); accD.y = fmaf(w, f.y, accD.y);
    }

    accS.x += __shfl_xor(accS.x, 32, 64);
    accS.y += __shfl_xor(accS.y, 32, 64);
    accD.x += __shfl_xor(accD.x, 32, 64);
    accD.y += __shfl_xor(accD.y, 32, 64);
    if (grp == 0) {
        aggS[(size_t)wid * 32 + col] = make_float2(dS * accS.x, dS * accS.y);
        aggD[(size_t)wid * 32 + col] = make_float2(dD * accD.x, dD * accD.y);
    }
}

// ---------------- apply: h = relu(aggS@Wa + aggD@Wb + ba + bb) [+ head] ----------------
// Fully static register arrays: acc[64] with unrolled j, k via float4 tiles with
// component-static extraction. W reads are wave-uniform -> scalar loads (SMEM pipe).

template <int HEAD>
__global__ __launch_bounds__(256) void apply_k(const float2* __restrict__ aggSp,
                                               const float2* __restrict__ aggDp,
                                               const float* __restrict__ Wa,
                                               const float* __restrict__ Wb,
                                               const float* __restrict__ ba,
                                               const float* __restrict__ bb,
                                               const float* __restrict__ Wlin,
                                               const float* __restrict__ blin,
                                               unsigned* __restrict__ outH,
                                               float* __restrict__ out3, int n) {
    int row = blockIdx.x * 256 + threadIdx.x;
    if (row >= n) return;
    const float4* pS = reinterpret_cast<const float4*>(aggSp + (size_t)row * 32);
    const float4* pD = reinterpret_cast<const float4*>(aggDp + (size_t)row * 32);

    float acc[64];
#pragma unroll
    for (int j = 0; j < 64; j++) acc[j] = ba[j] + bb[j];

#pragma unroll
    for (int kt = 0; kt < 16; kt++) {
        float4 aS = pS[kt];
        float4 aD = pD[kt];
#pragma unroll
        for (int c = 0; c < 4; c++) {
            int k = 4 * kt + c;
            float a1 = (c == 0) ? aS.x : (c == 1) ? aS.y : (c == 2) ? aS.z : aS.w;
            float a2 = (c == 0) ? aD.x : (c == 1) ? aD.y : (c == 2) ? aD.z : aD.w;
            const float* wra = Wa + k * 64;
            const float* wrb = Wb + k * 64;
#pragma unroll
            for (int j = 0; j < 64; j++)
                acc[j] = fmaf(a1, wra[j], fmaf(a2, wrb[j], acc[j]));
        }
    }

    if (HEAD == 0) {
        unsigned u[32];
#pragma unroll
        for (int p = 0; p < 32; p++)
            u[p] = f2h2(fmaxf(acc[2 * p], 0.0f), fmaxf(acc[2 * p + 1], 0.0f));
        uint4* o = reinterpret_cast<uint4*>(outH + (size_t)row * 32);
#pragma unroll
        for (int q = 0; q < 8; q++)
            o[q] = make_uint4(u[4 * q], u[4 * q + 1], u[4 * q + 2], u[4 * q + 3]);
    } else {
        float h0 = blin[0], h1 = blin[1], h2 = blin[2];
#pragma unroll
        for (int j = 0; j < 64; j++) {
            float v = fmaxf(acc[j], 0.0f);
            h0 = fmaf(v, Wlin[j * 3 + 0], h0);
            h1 = fmaf(v, Wlin[j * 3 + 1], h1);
            h2 = fmaf(v, Wlin[j * 3 + 2], h2);
        }
        out3[row * 3 + 0] = h0;
        out3[row * 3 + 1] = h1;
        out3[row * 3 + 2] = h2;
    }
}

extern "C" void kernel_launch(void* const* d_in, const int* in_sizes, int n_in,
                              void* d_out, int out_size, void* d_ws, size_t ws_size,
                              hipStream_t stream) {
    const float* x    = (const float*)d_in[0];
    const int*   eis  = (const int*)d_in[1];
    const int*   eid  = (const int*)d_in[2];
    const float* W1s  = (const float*)d_in[3];
    const float* b1s  = (const float*)d_in[4];
    const float* W1d  = (const float*)d_in[5];
    const float* b1d  = (const float*)d_in[6];
    const float* W2s  = (const float*)d_in[7];
    const float* b2s  = (const float*)d_in[8];
    const float* W2d  = (const float*)d_in[9];
    const float* b2d  = (const float*)d_in[10];
    const float* Wlin = (const float*)d_in[11];
    const float* blin = (const float*)d_in[12];

    const int N  = NN;
    const int Es = in_sizes[1] / 2;
    const int Ed = in_sizes[2] / 2;
    int Emax = (Es > Ed) ? Es : Ed;

    // workspace layout (4B elements)
    int*   cntS  = (int*)d_ws;
    int*   cntD  = cntS + NBK;
    int*   baseS = cntD + NBK;
    int*   baseD = baseS + (NBK + 1);
    int*   curS  = baseD + (NBK + 1);
    int*   curD  = curS + NBK;
    int*   offsS = curD + NBK;                  // [N+4]
    int*   offsD = offsS + (N + 4);             // [N+4]
    float* dinvS = (float*)(offsD + (N + 4));   // [N]
    float* dinvD = dinvS + N;                   // [N]
    unsigned* recS = (unsigned*)(dinvD + N);    // [Es]
    unsigned* recD = recS + Es;                 // [Ed]
    unsigned* x16  = recD + Ed;                 // [N*32] fp16 features
    unsigned* h16  = x16 + (size_t)N * 32;      // [N*32] fp16 layer-1 output
    float2* aggS = (float2*)(h16 + (size_t)N * 32);  // [N*32] float2
    float2* aggD = aggS + (size_t)N * 32;            // [N*32] float2

    // ---- feature convert + CSR build ----
    hipMemsetAsync(cntS, 0, (size_t)2 * NBK * sizeof(int), stream);
    cvt_x<<<(N * 16 + 255) / 256, 256, 0, stream>>>(x, x16, N * 16);
    dim3 egrid((Emax + CHUNK - 1) / CHUNK, 2);
    bucket_count<<<egrid, 256, 0, stream>>>(eis, Es, eid, Ed, cntS, cntD);
    bucket_scan<<<2, 256, 0, stream>>>(cntS, cntD, baseS, baseD, curS, curD, offsS, offsD);
    bucket_scatter<<<egrid, 256, 0, stream>>>(eis, Es, eid, Ed, curS, curD, recS, recD);
    dim3 fgrid(NBK, 2);
    bucket_finalize<<<fgrid, 256, 0, stream>>>(baseS, baseD, recS, recD, offsS, offsD,
                                               dinvS, dinvD);
    pack_rec<<<(Emax + 255) / 256, 256, 0, stream>>>(recS, Es, recD, Ed, dinvS, dinvD);

    int gatherBlocks = (N * 64 + 255) / 256;
    int applyBlocks = (N + 255) / 256;

    // ---- layer 1: aggregate x, then apply W ----
    gather_agg<<<gatherBlocks, 256, 0, stream>>>(offsS, recS, offsD, recD, x16,
                                                 dinvS, dinvD, aggS, aggD, N);
    apply_k<0><<<applyBlocks, 256, 0, stream>>>(aggS, aggD, W1s, W1d, b1s, b1d,
                                                nullptr, nullptr, h16, nullptr, N);

    // ---- layer 2: aggregate h1, then apply W + head ----
    gather_agg<<<gatherBlocks, 256, 0, stream>>>(offsS, recS, offsD, recD, h16,
                                                 dinvS, dinvD, aggS, aggD, N);
    apply_k<1><<<applyBlocks, 256, 0, stream>>>(aggS, aggD, W2s, W2d, b2s, b2d,
                                                Wlin, blin, nullptr, (float*)d_out, N);
}

// Round 7
// 191.950 us; speedup vs baseline: 4.8190x; 1.5528x over previous
//
#include <hip/hip_runtime.h>
#include <hip/hip_fp16.h>

#define NN 50000
#define BSHIFT 8
#define NBK ((NN + 255) >> 8)   // 196 buckets of 256 nodes
#define CHUNK 4096
#define CAP 8192

typedef __attribute__((ext_vector_type(8))) _Float16 f16x8;
typedef __attribute__((ext_vector_type(4))) float f32x4;

__device__ __forceinline__ float recw(unsigned r) {
    unsigned short us = (unsigned short)(r >> 16);
    __half h;
    __builtin_memcpy(&h, &us, 2);
    return __half2float(h);
}
__device__ __forceinline__ float2 h2f2(unsigned v) {
    __half2 h;
    __builtin_memcpy(&h, &v, 4);
    return __half22float2(h);
}
__device__ __forceinline__ unsigned f2h2(float a, float b) {
    __half2 h = __floats2half2_rn(a, b);
    unsigned u;
    __builtin_memcpy(&u, &h, 4);
    return u;
}
__device__ __forceinline__ f16x8 as_f16x8(uint4 v) {
    f16x8 r;
    __builtin_memcpy(&r, &v, 16);
    return r;
}
__device__ __forceinline__ unsigned short f2h1(float v) {
    __half h = __float2half(v);
    unsigned short us;
    __builtin_memcpy(&us, &h, 2);
    return us;
}

// ---------------- x -> fp16 convert ----------------

__global__ __launch_bounds__(256) void cvt_x(const float* __restrict__ x,
                                             unsigned* __restrict__ x16, int total4) {
    int i = blockIdx.x * 256 + threadIdx.x;
    if (i >= total4) return;
    float4 v = reinterpret_cast<const float4*>(x)[i];
    uint2 o;
    o.x = f2h2(v.x, v.y);
    o.y = f2h2(v.z, v.w);
    reinterpret_cast<uint2*>(x16)[i] = o;
}

// ---------------- W -> fp16 fragment-order pack (both layers) ----------------
// B matrix per layer: [128,64] = stack(Ws, Wd). Fragment (ks,jt): lane l, elem j
// holds B[ks*32 + (l>>4)*8 + j][jt*16 + (l&15)].
// Bp layout: layer*8192 + (((ks*4 + jt)*64 + l)*8 + j)

__global__ __launch_bounds__(256) void prep_w(const float* __restrict__ W1s,
                                              const float* __restrict__ W1d,
                                              const float* __restrict__ W2s,
                                              const float* __restrict__ W2d,
                                              unsigned short* __restrict__ Bp) {
    int idx = blockIdx.x * 256 + threadIdx.x;
    if (idx >= 16384) return;
    int layer = idx >> 13;
    int rem = idx & 8191;
    int j = rem & 7;
    int l = (rem >> 3) & 63;
    int jt = (rem >> 9) & 3;
    int ks = rem >> 11;
    int k = ks * 32 + (l >> 4) * 8 + j;
    int col = jt * 16 + (l & 15);
    const float* Ws = layer ? W2s : W1s;
    const float* Wd = layer ? W2d : W1d;
    float v = (k < 64) ? Ws[k * 64 + col] : Wd[(k - 64) * 64 + col];
    Bp[idx] = f2h1(v);
}

// ---------------- pass A: per-bucket edge counts ----------------

__global__ __launch_bounds__(256) void bucket_count(const int* __restrict__ eiS, int Es,
                                                    const int* __restrict__ eiD, int Ed,
                                                    int* __restrict__ cntS,
                                                    int* __restrict__ cntD) {
    __shared__ int h[NBK];
    int rel = blockIdx.y;
    const int* dst = rel ? (eiD + Ed) : (eiS + Es);
    int E = rel ? Ed : Es;
    int* cnt = rel ? cntD : cntS;
    int base = blockIdx.x * CHUNK;
    if (base >= E) return;
    for (int i = threadIdx.x; i < NBK; i += 256) h[i] = 0;
    __syncthreads();
    int end = (base + CHUNK < E) ? base + CHUNK : E;
    for (int e = base + threadIdx.x; e < end; e += 256)
        atomicAdd(&h[dst[e] >> BSHIFT], 1);
    __syncthreads();
    for (int i = threadIdx.x; i < NBK; i += 256)
        if (h[i]) atomicAdd(&cnt[i], h[i]);
}

// ---------------- pass B: scan bucket counts ----------------

__global__ __launch_bounds__(256) void bucket_scan(const int* __restrict__ cntS,
                                                   const int* __restrict__ cntD,
                                                   int* __restrict__ baseS,
                                                   int* __restrict__ baseD,
                                                   int* __restrict__ curS,
                                                   int* __restrict__ curD,
                                                   int* __restrict__ offsS,
                                                   int* __restrict__ offsD) {
    __shared__ int sA[256], sB[256];
    const int* cnt = blockIdx.x ? cntD : cntS;
    int* base = blockIdx.x ? baseD : baseS;
    int* cur  = blockIdx.x ? curD : curS;
    int* offs = blockIdx.x ? offsD : offsS;
    int t = threadIdx.x;
    int v = (t < NBK) ? cnt[t] : 0;
    sA[t] = v;
    __syncthreads();
    int* pin = sA; int* pout = sB;
    for (int st = 1; st < 256; st <<= 1) {
        int x = pin[t];
        if (t >= st) x += pin[t - st];
        pout[t] = x;
        __syncthreads();
        int* tmp = pin; pin = pout; pout = tmp;
    }
    int incl = pin[t];
    int excl = incl - v;
    if (t < NBK) { base[t] = excl; cur[t] = excl; }
    if (t == NBK - 1) { base[NBK] = incl; offs[NN] = incl; }
}

// ---------------- pass C: scatter packed records ----------------

__global__ __launch_bounds__(256) void bucket_scatter(const int* __restrict__ eiS, int Es,
                                                      const int* __restrict__ eiD, int Ed,
                                                      int* __restrict__ curS,
                                                      int* __restrict__ curD,
                                                      unsigned* __restrict__ recS,
                                                      unsigned* __restrict__ recD) {
    __shared__ int h[NBK];
    __shared__ int rb[NBK];
    int rel = blockIdx.y;
    const int* ei = rel ? eiD : eiS;
    int E = rel ? Ed : Es;
    int* cur = rel ? curD : curS;
    unsigned* rec = rel ? recD : recS;
    int base = blockIdx.x * CHUNK;
    if (base >= E) return;
    const int* src = ei;
    const int* dst = ei + E;
    int end = (base + CHUNK < E) ? base + CHUNK : E;

    for (int i = threadIdx.x; i < NBK; i += 256) h[i] = 0;
    __syncthreads();
    for (int e = base + threadIdx.x; e < end; e += 256)
        atomicAdd(&h[dst[e] >> BSHIFT], 1);
    __syncthreads();
    for (int i = threadIdx.x; i < NBK; i += 256) {
        int c = h[i];
        rb[i] = c ? atomicAdd(&cur[i], c) : 0;
    }
    __syncthreads();
    for (int i = threadIdx.x; i < NBK; i += 256) h[i] = 0;
    __syncthreads();
    for (int e = base + threadIdx.x; e < end; e += 256) {
        int d = dst[e];
        int s = src[e];
        int b = d >> BSHIFT;
        int p = atomicAdd(&h[b], 1);
        rec[rb[b] + p] = (unsigned)s | ((unsigned)(d & 255) << 16);
    }
}

// ---------------- pass D: per-bucket finalize ----------------

__global__ __launch_bounds__(256) void bucket_finalize(const int* __restrict__ baseS,
                                                       const int* __restrict__ baseD,
                                                       unsigned* __restrict__ recS,
                                                       unsigned* __restrict__ recD,
                                                       int* __restrict__ offsS,
                                                       int* __restrict__ offsD,
                                                       float* __restrict__ dinvS,
                                                       float* __restrict__ dinvD) {
    __shared__ unsigned recs[CAP];
    __shared__ int lc[256], sA[256], sB[256];
    int rel = blockIdx.y;
    const int* base = rel ? baseD : baseS;
    unsigned* rec = rel ? recD : recS;
    int* offs = rel ? offsD : offsS;
    float* dinv = rel ? dinvD : dinvS;
    int b = blockIdx.x;
    int b0 = base[b], b1 = base[b + 1];
    int cnt = b1 - b0;
    int t = threadIdx.x;
    lc[t] = 0;
    __syncthreads();
    for (int i = t; i < cnt; i += 256) {
        unsigned r = rec[b0 + i];
        if (i < CAP) recs[i] = r;
        atomicAdd(&lc[r >> 16], 1);
    }
    __syncthreads();
    int v = lc[t];
    int g = (b << BSHIFT) + t;
    if (g < NN) dinv[g] = rsqrtf((float)v + 1.0f);
    sA[t] = v;
    __syncthreads();
    int* pin = sA; int* pout = sB;
    for (int st = 1; st < 256; st <<= 1) {
        int x = pin[t];
        if (t >= st) x += pin[t - st];
        pout[t] = x;
        __syncthreads();
        int* tmp = pin; pin = pout; pout = tmp;
    }
    int excl = pin[t] - v;
    if (g < NN) offs[g] = b0 + excl;
    lc[t] = excl;
    __syncthreads();
    for (int i = t; i < cnt; i += 256) {
        unsigned r = (i < CAP) ? recs[i] : rec[b0 + i];
        int p = atomicAdd(&lc[r >> 16], 1);
        rec[b0 + p] = r & 0xFFFFu;
    }
}

// ---------------- pack: rec = src | half(dinv[src])<<16 ----------------

__global__ __launch_bounds__(256) void pack_rec(unsigned* __restrict__ recS, int Es,
                                                unsigned* __restrict__ recD, int Ed,
                                                const float* __restrict__ dinvS,
                                                const float* __restrict__ dinvD) {
    int i = blockIdx.x * 256 + threadIdx.x;
    if (i < Es) {
        unsigned s = recS[i] & 0xFFFFu;
        recS[i] = s | ((unsigned)f2h1(dinvS[s]) << 16);
    }
    if (i < Ed) {
        unsigned s = recD[i] & 0xFFFFu;
        recD[i] = s | ((unsigned)f2h1(dinvD[s]) << 16);
    }
}

// ---------------- gather both relations -> fp16 A matrix [n,128] ----------------
// A row: halves 0..63 = dS*aggS, 64..127 = dD*aggD (K-concat for the MFMA apply).

__global__ __launch_bounds__(256) void gather_agg(const int* __restrict__ offsS,
                                                  const unsigned* __restrict__ recS,
                                                  const int* __restrict__ offsD,
                                                  const unsigned* __restrict__ recD,
                                                  const unsigned* __restrict__ feat,
                                                  const float* __restrict__ dinvS,
                                                  const float* __restrict__ dinvD,
                                                  unsigned* __restrict__ A, int n) {
    int wid = (blockIdx.x * 256 + threadIdx.x) >> 6;
    int lane = threadIdx.x & 63;
    if (wid >= n) return;
    int grp = lane >> 5;
    int col = lane & 31;

    float dS = dinvS[wid];
    float dD = dinvD[wid];

    unsigned selfv = feat[(size_t)wid * 32 + col];
    float2 sf = h2f2(selfv);
    float ws0 = grp ? 0.0f : dS;
    float wd0 = grp ? 0.0f : dD;
    float2 accS = make_float2(ws0 * sf.x, ws0 * sf.y);
    float2 accD = make_float2(wd0 * sf.x, wd0 * sf.y);

    int eS = offsS[wid], eS1 = offsS[wid + 1];
    int eD = offsD[wid], eD1 = offsD[wid + 1];

    while (eS + 8 <= eS1 && eD + 8 <= eD1) {
        unsigned rs0 = recS[eS + 0 + grp], rs1 = recS[eS + 2 + grp];
        unsigned rs2 = recS[eS + 4 + grp], rs3 = recS[eS + 6 + grp];
        unsigned rd0 = recD[eD + 0 + grp], rd1 = recD[eD + 2 + grp];
        unsigned rd2 = recD[eD + 4 + grp], rd3 = recD[eD + 6 + grp];
        unsigned vs0 = feat[(size_t)(rs0 & 0xFFFFu) * 32 + col];
        unsigned vs1 = feat[(size_t)(rs1 & 0xFFFFu) * 32 + col];
        unsigned vs2 = feat[(size_t)(rs2 & 0xFFFFu) * 32 + col];
        unsigned vs3 = feat[(size_t)(rs3 & 0xFFFFu) * 32 + col];
        unsigned vd0 = feat[(size_t)(rd0 & 0xFFFFu) * 32 + col];
        unsigned vd1 = feat[(size_t)(rd1 & 0xFFFFu) * 32 + col];
        unsigned vd2 = feat[(size_t)(rd2 & 0xFFFFu) * 32 + col];
        unsigned vd3 = feat[(size_t)(rd3 & 0xFFFFu) * 32 + col];
        float w; float2 f;
        w = recw(rs0); f = h2f2(vs0); accS.x = fmaf(w, f.x, accS.x); accS.y = fmaf(w, f.y, accS.y);
        w = recw(rs1); f = h2f2(vs1); accS.x = fmaf(w, f.x, accS.x); accS.y = fmaf(w, f.y, accS.y);
        w = recw(rs2); f = h2f2(vs2); accS.x = fmaf(w, f.x, accS.x); accS.y = fmaf(w, f.y, accS.y);
        w = recw(rs3); f = h2f2(vs3); accS.x = fmaf(w, f.x, accS.x); accS.y = fmaf(w, f.y, accS.y);
        w = recw(rd0); f = h2f2(vd0); accD.x = fmaf(w, f.x, accD.x); accD.y = fmaf(w, f.y, accD.y);
        w = recw(rd1); f = h2f2(vd1); accD.x = fmaf(w, f.x, accD.x); accD.y = fmaf(w, f.y, accD.y);
        w = recw(rd2); f = h2f2(vd2); accD.x = fmaf(w, f.x, accD.x); accD.y = fmaf(w, f.y, accD.y);
        w = recw(rd3); f = h2f2(vd3); accD.x = fmaf(w, f.x, accD.x); accD.y = fmaf(w, f.y, accD.y);
        eS += 8; eD += 8;
    }
    while (eS + 2 <= eS1) {
        unsigned r = recS[eS + grp];
        unsigned v = feat[(size_t)(r & 0xFFFFu) * 32 + col];
        float w = recw(r); float2 f = h2f2(v);
        accS.x = fmaf(w, f.x, accS.x); accS.y = fmaf(w, f.y, accS.y);
        eS += 2;
    }
    if (eS < eS1) {
        unsigned r = recS[eS];
        unsigned v = feat[(size_t)(r & 0xFFFFu) * 32 + col];
        float w = grp ? 0.0f : recw(r); float2 f = h2f2(v);
        accS.x = fmaf(w, f.x, accS.x); accS.y = fmaf(w, f.y, accS.y);
    }
    while (eD + 2 <= eD1) {
        unsigned r = recD[eD + grp];
        unsigned v = feat[(size_t)(r & 0xFFFFu) * 32 + col];
        float w = recw(r); float2 f = h2f2(v);
        accD.x = fmaf(w, f.x, accD.x); accD.y = fmaf(w, f.y, accD.y);
        eD += 2;
    }
    if (eD < eD1) {
        unsigned r = recD[eD];
        unsigned v = feat[(size_t)(r & 0xFFFFu) * 32 + col];
        float w = grp ? 0.0f : recw(r); float2 f = h2f2(v);
        accD.x = fmaf(w, f.x, accD.x); accD.y = fmaf(w, f.y, accD.y);
    }

    accS.x += __shfl_xor(accS.x, 32, 64);
    accS.y += __shfl_xor(accS.y, 32, 64);
    accD.x += __shfl_xor(accD.x, 32, 64);
    accD.y += __shfl_xor(accD.y, 32, 64);
    if (grp == 0) {
        A[(size_t)wid * 64 + col]      = f2h2(dS * accS.x, dS * accS.y);
        A[(size_t)wid * 64 + 32 + col] = f2h2(dD * accD.x, dD * accD.y);
    }
}

// ---------------- apply via fp16 MFMA: [n,128] @ [128,64], bias+relu epilogue ----------------
// One wave per 16 rows. 4 K-steps x 4 j-tiles of mfma_f32_16x16x32_f16.
// HEAD=0: write h fp16 [n,64]. HEAD=1: fuse 64->3 head with 16-lane shfl reduce.

#define STORE_JT(ACC, JT)                                                     \
    {                                                                         \
        int colj = (JT) * 16 + lr;                                            \
        float bs = ba[colj] + bb[colj];                                       \
        _Pragma("unroll")                                                     \
        for (int r = 0; r < 4; r++) {                                         \
            float v = fmaxf(ACC[r] + bs, 0.0f);                               \
            outH[(size_t)(m0 + lh * 4 + r) * 64 + colj] = f2h1(v);            \
        }                                                                     \
    }

#define HEAD_JT(ACC, JT)                                                      \
    {                                                                         \
        int colj = (JT) * 16 + lr;                                            \
        float bs = ba[colj] + bb[colj];                                       \
        float w0 = Wlin[colj * 3 + 0];                                        \
        float w1 = Wlin[colj * 3 + 1];                                        \
        float w2 = Wlin[colj * 3 + 2];                                        \
        _Pragma("unroll")                                                     \
        for (int r = 0; r < 4; r++) {                                         \
            float v = fmaxf(ACC[r] + bs, 0.0f);                               \
            h0[r] = fmaf(v, w0, h0[r]);                                       \
            h1[r] = fmaf(v, w1, h1[r]);                                       \
            h2[r] = fmaf(v, w2, h2[r]);                                       \
        }                                                                     \
    }

template <int HEAD>
__global__ __launch_bounds__(256) void apply_mfma(const unsigned* __restrict__ A,
                                                  const unsigned short* __restrict__ Bp,
                                                  const float* __restrict__ ba,
                                                  const float* __restrict__ bb,
                                                  const float* __restrict__ Wlin,
                                                  const float* __restrict__ blin,
                                                  unsigned short* __restrict__ outH,
                                                  float* __restrict__ out3, int n) {
    int wid = (blockIdx.x * 256 + threadIdx.x) >> 6;
    int l = threadIdx.x & 63;
    int m0 = wid * 16;
    if (m0 >= n) return;
    int lr = l & 15;
    int lh = l >> 4;

    const uint4* Bv = reinterpret_cast<const uint4*>(Bp);
    f32x4 acc0 = {0.f, 0.f, 0.f, 0.f};
    f32x4 acc1 = {0.f, 0.f, 0.f, 0.f};
    f32x4 acc2 = {0.f, 0.f, 0.f, 0.f};
    f32x4 acc3 = {0.f, 0.f, 0.f, 0.f};

#pragma unroll
    for (int ks = 0; ks < 4; ks++) {
        uint4 av = *reinterpret_cast<const uint4*>(A + (size_t)(m0 + lr) * 64 + ks * 16 + lh * 4);
        f16x8 af = as_f16x8(av);
        uint4 b0 = Bv[(ks * 4 + 0) * 64 + l];
        uint4 b1 = Bv[(ks * 4 + 1) * 64 + l];
        uint4 b2 = Bv[(ks * 4 + 2) * 64 + l];
        uint4 b3 = Bv[(ks * 4 + 3) * 64 + l];
        acc0 = __builtin_amdgcn_mfma_f32_16x16x32_f16(af, as_f16x8(b0), acc0, 0, 0, 0);
        acc1 = __builtin_amdgcn_mfma_f32_16x16x32_f16(af, as_f16x8(b1), acc1, 0, 0, 0);
        acc2 = __builtin_amdgcn_mfma_f32_16x16x32_f16(af, as_f16x8(b2), acc2, 0, 0, 0);
        acc3 = __builtin_amdgcn_mfma_f32_16x16x32_f16(af, as_f16x8(b3), acc3, 0, 0, 0);
    }

    if (HEAD == 0) {
        STORE_JT(acc0, 0)
        STORE_JT(acc1, 1)
        STORE_JT(acc2, 2)
        STORE_JT(acc3, 3)
    } else {
        float h0[4] = {0.f, 0.f, 0.f, 0.f};
        float h1[4] = {0.f, 0.f, 0.f, 0.f};
        float h2[4] = {0.f, 0.f, 0.f, 0.f};
        HEAD_JT(acc0, 0)
        HEAD_JT(acc1, 1)
        HEAD_JT(acc2, 2)
        HEAD_JT(acc3, 3)
#pragma unroll
        for (int st = 1; st < 16; st <<= 1) {
#pragma unroll
            for (int r = 0; r < 4; r++) {
                h0[r] += __shfl_xor(h0[r], st, 64);
                h1[r] += __shfl_xor(h1[r], st, 64);
                h2[r] += __shfl_xor(h2[r], st, 64);
            }
        }
        if (lr == 0) {
#pragma unroll
            for (int r = 0; r < 4; r++) {
                int row = m0 + lh * 4 + r;
                out3[row * 3 + 0] = h0[r] + blin[0];
                out3[row * 3 + 1] = h1[r] + blin[1];
                out3[row * 3 + 2] = h2[r] + blin[2];
            }
        }
    }
}

extern "C" void kernel_launch(void* const* d_in, const int* in_sizes, int n_in,
                              void* d_out, int out_size, void* d_ws, size_t ws_size,
                              hipStream_t stream) {
    const float* x    = (const float*)d_in[0];
    const int*   eis  = (const int*)d_in[1];
    const int*   eid  = (const int*)d_in[2];
    const float* W1s  = (const float*)d_in[3];
    const float* b1s  = (const float*)d_in[4];
    const float* W1d  = (const float*)d_in[5];
    const float* b1d  = (const float*)d_in[6];
    const float* W2s  = (const float*)d_in[7];
    const float* b2s  = (const float*)d_in[8];
    const float* W2d  = (const float*)d_in[9];
    const float* b2d  = (const float*)d_in[10];
    const float* Wlin = (const float*)d_in[11];
    const float* blin = (const float*)d_in[12];

    const int N  = NN;
    const int Es = in_sizes[1] / 2;
    const int Ed = in_sizes[2] / 2;
    int Emax = (Es > Ed) ? Es : Ed;

    // workspace layout (4B units; every offset multiple of 4 units -> 16B aligned)
    int*   cntS  = (int*)d_ws;                  // [196]
    int*   cntD  = cntS + NBK;                  // [196]
    int*   baseS = cntD + NBK;                  // [200]
    int*   baseD = baseS + (NBK + 4);           // [200]
    int*   curS  = baseD + (NBK + 4);           // [196]
    int*   curD  = curS + NBK;                  // [196]
    int*   offsS = curD + NBK;                  // [50004]
    int*   offsD = offsS + (N + 4);             // [50004]
    float* dinvS = (float*)(offsD + (N + 4));   // [50000]
    float* dinvD = dinvS + N;                   // [50000]
    unsigned* recS = (unsigned*)(dinvD + N);    // [Es]
    unsigned* recD = recS + Es;                 // [Ed]
    unsigned* x16  = recD + Ed;                 // [N*32] fp16 x features
    unsigned* h16u = x16 + (size_t)N * 32;      // [N*32] fp16 layer-1 output
    unsigned* Abuf = h16u + (size_t)N * 32;     // [N*64] fp16 A matrix (aggS|aggD)
    unsigned short* Bp = (unsigned short*)(Abuf + (size_t)N * 64);  // [16384] halves
    unsigned short* h16 = (unsigned short*)h16u;

    // ---- prep: feature convert, W pack, CSR build ----
    hipMemsetAsync(cntS, 0, (size_t)2 * NBK * sizeof(int), stream);
    cvt_x<<<(N * 16 + 255) / 256, 256, 0, stream>>>(x, x16, N * 16);
    prep_w<<<64, 256, 0, stream>>>(W1s, W1d, W2s, W2d, Bp);
    dim3 egrid((Emax + CHUNK - 1) / CHUNK, 2);
    bucket_count<<<egrid, 256, 0, stream>>>(eis, Es, eid, Ed, cntS, cntD);
    bucket_scan<<<2, 256, 0, stream>>>(cntS, cntD, baseS, baseD, curS, curD, offsS, offsD);
    bucket_scatter<<<egrid, 256, 0, stream>>>(eis, Es, eid, Ed, curS, curD, recS, recD);
    dim3 fgrid(NBK, 2);
    bucket_finalize<<<fgrid, 256, 0, stream>>>(baseS, baseD, recS, recD, offsS, offsD,
                                               dinvS, dinvD);
    pack_rec<<<(Emax + 255) / 256, 256, 0, stream>>>(recS, Es, recD, Ed, dinvS, dinvD);

    int gatherBlocks = (N * 64 + 255) / 256;
    int mtiles = (N + 15) / 16;                       // 3125 waves
    int applyBlocks = (mtiles * 64 + 255) / 256;      // 782 blocks

    // ---- layer 1 ----
    gather_agg<<<gatherBlocks, 256, 0, stream>>>(offsS, recS, offsD, recD, x16,
                                                 dinvS, dinvD, Abuf, N);
    apply_mfma<0><<<applyBlocks, 256, 0, stream>>>(Abuf, Bp, b1s, b1d,
                                                   nullptr, nullptr, h16, nullptr, N);

    // ---- layer 2 (head fused) ----
    gather_agg<<<gatherBlocks, 256, 0, stream>>>(offsS, recS, offsD, recD, h16u,
                                                 dinvS, dinvD, Abuf, N);
    apply_mfma<1><<<applyBlocks, 256, 0, stream>>>(Abuf, Bp + 8192, b2s, b2d,
                                                   Wlin, blin, nullptr, (float*)d_out, N);
}